// Round 15
// baseline (1347.398 us; speedup 1.0000x reference)
//
#include <hip/hip_runtime.h>
#include <hip/hip_bf16.h>
#include <cstdint>
#include <cstddef>

#define D_IN    32
#define D_MAIN  256
#define D_BLOCK 512
#define CTX     96
#define K_PRE   128
#define NQ      1024
#define NTRAIN  100000
#define NS      6250      // sampled candidates (stride 16)
#define TH_RANK 48        // sample rank for threshold -> ~768 expected candidates
#define CAND_CAP 2048
#define SLOTS   12        // per (row, 128-col tile) candidate slots

typedef __attribute__((ext_vector_type(8))) short bf16x8;
typedef __attribute__((ext_vector_type(8))) _Float16 f16x8;
typedef __attribute__((ext_vector_type(4))) float f32x4;
typedef __hip_bfloat16 bf;
typedef unsigned long long u64;

#define GLL(gp, lp) __builtin_amdgcn_global_load_lds( \
    (const __attribute__((address_space(1))) void*)(gp), \
    (__attribute__((address_space(3))) void*)(lp), 16, 0, 0)

// ---------------------------------------------------------------------------
// Plain bf16 MFMA GEMM: C = act(alpha*(A@B^T) + biasScale*bias[n])
// 128x128 tile, BK=32, 4 waves, 16x16x32 MFMA, XOR-swizzled LDS staging.
// ---------------------------------------------------------------------------
__global__ __launch_bounds__(256) void gemm_bf16(
    const bf* __restrict__ A, const bf* __restrict__ B,
    int M, int N, int K, float alpha,
    const float* __restrict__ bias, float biasScale,
    float* __restrict__ Cf, bf* __restrict__ Ch, int relu)
{
    __shared__ __align__(16) char smem[16384];
    const int tid = threadIdx.x;
    const int w   = tid >> 6;
    const int lam = tid & 63;
    const int bm  = blockIdx.y * 128;
    const int bn  = blockIdx.x * 128;
    const int wm  = w >> 1, wn = w & 1;

    f32x4 acc[4][4];
#pragma unroll
    for (int i = 0; i < 4; ++i)
#pragma unroll
        for (int j = 0; j < 4; ++j) acc[i][j] = (f32x4){0.f, 0.f, 0.f, 0.f};

    const int r0s  = w * 16 + (lam >> 2);
    const int slot = lam & 3;
    const int g0   = slot ^ ((r0s >> 1) & 3);
    const int g1   = slot ^ (((r0s + 64) >> 1) & 3);
    const size_t strideAB = (size_t)K * 2;
    long ga0 = bm + r0s;      if (ga0 >= M) ga0 = M - 1;
    long ga1 = bm + r0s + 64; if (ga1 >= M) ga1 = M - 1;
    long gb0 = bn + r0s;      if (gb0 >= N) gb0 = N - 1;
    long gb1 = bn + r0s + 64; if (gb1 >= N) gb1 = N - 1;
    const char* pa0 = (const char*)A + (size_t)ga0 * strideAB + 16 * g0;
    const char* pa1 = (const char*)A + (size_t)ga1 * strideAB + 16 * g1;
    const char* pb0 = (const char*)B + (size_t)gb0 * strideAB + 16 * g0;
    const char* pb1 = (const char*)B + (size_t)gb1 * strideAB + 16 * g1;

    const int sread = (lam >> 4) ^ ((lam >> 1) & 3);
    const int abase = wm * 4096 + (lam & 15) * 64 + sread * 16;
    const int bbase = 8192 + wn * 4096 + (lam & 15) * 64 + sread * 16;

    for (int k0 = 0; k0 < K; k0 += 32) {
        __syncthreads();
        const size_t kb = 2 * (size_t)k0;
        GLL(pa0 + kb, smem + w * 1024);
        GLL(pa1 + kb, smem + 4096 + w * 1024);
        GLL(pb0 + kb, smem + 8192 + w * 1024);
        GLL(pb1 + kb, smem + 12288 + w * 1024);
        asm volatile("s_waitcnt vmcnt(0)" ::: "memory");
        __syncthreads();

        bf16x8 aF[4], bF[4];
#pragma unroll
        for (int i = 0; i < 4; ++i) aF[i] = *(const bf16x8*)(smem + abase + 1024 * i);
#pragma unroll
        for (int j = 0; j < 4; ++j) bF[j] = *(const bf16x8*)(smem + bbase + 1024 * j);
#pragma unroll
        for (int i = 0; i < 4; ++i)
#pragma unroll
            for (int j = 0; j < 4; ++j)
                acc[i][j] = __builtin_amdgcn_mfma_f32_16x16x32_bf16(aF[i], bF[j], acc[i][j], 0, 0, 0);
    }

    const int col0 = bn + wn * 64 + (lam & 15);
    const int row0 = bm + wm * 64 + ((lam >> 4) << 2);
#pragma unroll
    for (int j = 0; j < 4; ++j) {
        const int col = col0 + 16 * j;
        if (col >= N) continue;
        const float bv = bias ? biasScale * bias[col] : 0.f;
#pragma unroll
        for (int i = 0; i < 4; ++i) {
#pragma unroll
            for (int r = 0; r < 4; ++r) {
                const int row = row0 + 16 * i + r;
                if (row >= M) continue;
                float v = alpha * acc[i][j][r] + bv;
                if (relu) v = fmaxf(v, 0.f);
                const size_t idx = (size_t)row * N + col;
                if (Cf) Cf[idx] = v;
                if (Ch) Ch[idx] = __float2bfloat16(v);
            }
        }
    }
}

// ---------------------------------------------------------------------------
// Plain fp16 MFMA GEMM (train encoder): C = act(A@B^T + bias[n] (+ res16))
// Outputs: fp32 / fp16 / bf16 (any subset). res16 may alias Ch (same-index
// read-then-write within one thread).
// ---------------------------------------------------------------------------
__global__ __launch_bounds__(256) void gemm_fp16(
    const _Float16* __restrict__ A, const _Float16* __restrict__ B,
    int M, int N, int K,
    const float* __restrict__ bias, const _Float16* res16,
    float* __restrict__ Cf, _Float16* Ch, bf* __restrict__ Cb,
    int relu)
{
    __shared__ __align__(16) char smem[16384];
    const int tid = threadIdx.x;
    const int w   = tid >> 6;
    const int lam = tid & 63;
    const int bm  = blockIdx.y * 128;
    const int bn  = blockIdx.x * 128;
    const int wm  = w >> 1, wn = w & 1;

    f32x4 acc[4][4];
#pragma unroll
    for (int i = 0; i < 4; ++i)
#pragma unroll
        for (int j = 0; j < 4; ++j) acc[i][j] = (f32x4){0.f, 0.f, 0.f, 0.f};

    const int r0s  = w * 16 + (lam >> 2);
    const int slot = lam & 3;
    const int g0   = slot ^ ((r0s >> 1) & 3);
    const int g1   = slot ^ (((r0s + 64) >> 1) & 3);
    const size_t strideAB = (size_t)K * 2;
    long ga0 = bm + r0s;      if (ga0 >= M) ga0 = M - 1;
    long ga1 = bm + r0s + 64; if (ga1 >= M) ga1 = M - 1;
    long gb0 = bn + r0s;      if (gb0 >= N) gb0 = N - 1;
    long gb1 = bn + r0s + 64; if (gb1 >= N) gb1 = N - 1;
    const char* pa0 = (const char*)A + (size_t)ga0 * strideAB + 16 * g0;
    const char* pa1 = (const char*)A + (size_t)ga1 * strideAB + 16 * g1;
    const char* pb0 = (const char*)B + (size_t)gb0 * strideAB + 16 * g0;
    const char* pb1 = (const char*)B + (size_t)gb1 * strideAB + 16 * g1;

    const int sread = (lam >> 4) ^ ((lam >> 1) & 3);
    const int abase = wm * 4096 + (lam & 15) * 64 + sread * 16;
    const int bbase = 8192 + wn * 4096 + (lam & 15) * 64 + sread * 16;

    for (int k0 = 0; k0 < K; k0 += 32) {
        __syncthreads();
        const size_t kb = 2 * (size_t)k0;
        GLL(pa0 + kb, smem + w * 1024);
        GLL(pa1 + kb, smem + 4096 + w * 1024);
        GLL(pb0 + kb, smem + 8192 + w * 1024);
        GLL(pb1 + kb, smem + 12288 + w * 1024);
        asm volatile("s_waitcnt vmcnt(0)" ::: "memory");
        __syncthreads();

        f16x8 aF[4], bF[4];
#pragma unroll
        for (int i = 0; i < 4; ++i) aF[i] = *(const f16x8*)(smem + abase + 1024 * i);
#pragma unroll
        for (int j = 0; j < 4; ++j) bF[j] = *(const f16x8*)(smem + bbase + 1024 * j);
#pragma unroll
        for (int i = 0; i < 4; ++i)
#pragma unroll
            for (int j = 0; j < 4; ++j)
                acc[i][j] = __builtin_amdgcn_mfma_f32_16x16x32_f16(aF[i], bF[j], acc[i][j], 0, 0, 0);
    }

    const int col0 = bn + wn * 64 + (lam & 15);
    const int row0 = bm + wm * 64 + ((lam >> 4) << 2);
#pragma unroll
    for (int j = 0; j < 4; ++j) {
        const int col = col0 + 16 * j;
        if (col >= N) continue;
        const float bv = bias ? bias[col] : 0.f;
#pragma unroll
        for (int i = 0; i < 4; ++i) {
#pragma unroll
            for (int r = 0; r < 4; ++r) {
                const int row = row0 + 16 * i + r;
                if (row >= M) continue;
                float v = acc[i][j][r] + bv;
                const size_t idx = (size_t)row * N + col;
                if (res16) v += (float)res16[idx];
                if (relu) v = fmaxf(v, 0.f);
                if (Cf) Cf[idx] = v;
                if (Ch) Ch[idx] = (_Float16)v;
                if (Cb) Cb[idx] = __float2bfloat16(v);
            }
        }
    }
}

// ---------------------------------------------------------------------------
// Filter GEMM, BM=256 tile (32 MFMA/K-step): chunk of Mrows=mtiles*256 rows.
// XCD-pinned 1D grid: b -> nl=b&7, mt=(b>>3)&(mtiles-1), nt=(b>>(3+mshift))*8+nl.
// A = 16KB LDS (4 staging issues), B = 8KB. acc[8][4] per wave (waves 2x2,
// each 128 rows x 64 cols). Per-element K accumulation order identical to
// gemm_bf16 -> scores bitwise equal to sampled pass. ATOMIC-FREE epilogue,
// coalesced cells (nt*Mrows + row).
// ---------------------------------------------------------------------------
__global__ __launch_bounds__(256) void gemm_bf16_filter(
    const bf* __restrict__ A, const bf* __restrict__ B,
    int Mrows, int N, int K, float alpha,
    const float* __restrict__ bias, float biasScale,
    const float* __restrict__ tau,
    u64* __restrict__ pool, int* __restrict__ cnt2, int nN, int mshift)
{
    __shared__ __align__(16) char smem[24576];   // A 16KB @0, B 8KB @16384
    __shared__ int lcnt[256];
    __shared__ float stau[256];
    __shared__ u64 lcand[256][SLOTS];
    const int bidx = blockIdx.x;
    const int nl = bidx & 7;
    const int mt = (bidx >> 3) & ((1 << mshift) - 1);
    const int nt = (bidx >> (3 + mshift)) * 8 + nl;
    if (nt >= nN) return;
    const int bm = mt * 256;
    const int bn = nt * 128;

    const int tid = threadIdx.x;
    const int w   = tid >> 6;
    const int lam = tid & 63;
    const int wm  = w >> 1, wn = w & 1;

    lcnt[tid] = 0;
    stau[tid] = tau[bm + tid];

    f32x4 acc[8][4];
#pragma unroll
    for (int i = 0; i < 8; ++i)
#pragma unroll
        for (int j = 0; j < 4; ++j) acc[i][j] = (f32x4){0.f, 0.f, 0.f, 0.f};

    const int r0s  = w * 16 + (lam >> 2);
    const int slot = lam & 3;
    const int g    = slot ^ ((r0s >> 1) & 3);   // invariant under +64/128/192
    const size_t strideAB = (size_t)K * 2;
    long ga0 = bm + r0s;       if (ga0 >= Mrows) ga0 = Mrows - 1;
    long ga1 = bm + r0s + 64;  if (ga1 >= Mrows) ga1 = Mrows - 1;
    long ga2 = bm + r0s + 128; if (ga2 >= Mrows) ga2 = Mrows - 1;
    long ga3 = bm + r0s + 192; if (ga3 >= Mrows) ga3 = Mrows - 1;
    long gb0 = bn + r0s;       if (gb0 >= N) gb0 = N - 1;
    long gb1 = bn + r0s + 64;  if (gb1 >= N) gb1 = N - 1;
    const char* pa0 = (const char*)A + (size_t)ga0 * strideAB + 16 * g;
    const char* pa1 = (const char*)A + (size_t)ga1 * strideAB + 16 * g;
    const char* pa2 = (const char*)A + (size_t)ga2 * strideAB + 16 * g;
    const char* pa3 = (const char*)A + (size_t)ga3 * strideAB + 16 * g;
    const char* pb0 = (const char*)B + (size_t)gb0 * strideAB + 16 * g;
    const char* pb1 = (const char*)B + (size_t)gb1 * strideAB + 16 * g;

    const int sread = (lam >> 4) ^ ((lam >> 1) & 3);
    const int abase = wm * 8192 + (lam & 15) * 64 + sread * 16;
    const int bbase = 16384 + wn * 4096 + (lam & 15) * 64 + sread * 16;

    for (int k0 = 0; k0 < K; k0 += 32) {
        __syncthreads();
        const size_t kb = 2 * (size_t)k0;
        GLL(pa0 + kb, smem + w * 1024);
        GLL(pa1 + kb, smem + 4096 + w * 1024);
        GLL(pa2 + kb, smem + 8192 + w * 1024);
        GLL(pa3 + kb, smem + 12288 + w * 1024);
        GLL(pb0 + kb, smem + 16384 + w * 1024);
        GLL(pb1 + kb, smem + 20480 + w * 1024);
        asm volatile("s_waitcnt vmcnt(0)" ::: "memory");
        __syncthreads();

        bf16x8 aF[8], bF[4];
#pragma unroll
        for (int i = 0; i < 8; ++i) aF[i] = *(const bf16x8*)(smem + abase + 1024 * i);
#pragma unroll
        for (int j = 0; j < 4; ++j) bF[j] = *(const bf16x8*)(smem + bbase + 1024 * j);
#pragma unroll
        for (int i = 0; i < 8; ++i)
#pragma unroll
            for (int j = 0; j < 4; ++j)
                acc[i][j] = __builtin_amdgcn_mfma_f32_16x16x32_bf16(aF[i], bF[j], acc[i][j], 0, 0, 0);
    }

    const int col0 = bn + wn * 64 + (lam & 15);
    const int lrow0 = wm * 128 + ((lam >> 4) << 2);
#pragma unroll
    for (int j = 0; j < 4; ++j) {
        const int col = col0 + 16 * j;
        if (col >= N) continue;
        const float bv = biasScale * bias[col];
#pragma unroll
        for (int i = 0; i < 8; ++i) {
#pragma unroll
            for (int r = 0; r < 4; ++r) {
                const int lrow = lrow0 + 16 * i + r;
                const int row = bm + lrow;
                if (row >= Mrows) continue;
                const float v = alpha * acc[i][j][r] + bv;
                if (v >= stau[lrow]) {
                    const unsigned uu = __float_as_uint(v);
                    const unsigned key = (uu & 0x80000000u) ? ~uu : (uu | 0x80000000u);
                    const int s = atomicAdd(&lcnt[lrow], 1);
                    if (s < SLOTS)
                        lcand[lrow][s] = ((u64)(key ^ 0xffffffffu) << 32) | (unsigned)col;
                }
            }
        }
    }
    __syncthreads();
    {
        const int row = bm + tid;
        int c = lcnt[tid]; if (c > SLOTS) c = SLOTS;
        if (row < Mrows) {
            const size_t cell = (size_t)nt * Mrows + row;   // coalesced
            cnt2[cell] = c;
            u64* dst = pool + cell * SLOTS;
            for (int s = 0; s < c; ++s) dst[s] = lcand[tid][s];
        }
    }
}

// ---------------------------------------------------------------------------
// fp32 GEMM (query encoder / predictor; exact path)
// ---------------------------------------------------------------------------
#define TILE 64
#define KT   16
__global__ __launch_bounds__(256) void gemm_bias_act(
    const float* __restrict__ A, const float* __restrict__ B,
    const float* __restrict__ bias, float biasScale,
    const float* __restrict__ resid,
    float* __restrict__ C,
    int M, int N, int K, float alpha, int relu)
{
    __shared__ float As[KT][TILE + 4];
    __shared__ float Bs[KT][TILE + 4];
    const int bm = blockIdx.y * TILE;
    const int bn = blockIdx.x * TILE;
    const int tid = threadIdx.x;
    const int tx = tid & 15;
    const int ty = tid >> 4;
    const int lm = tid >> 2;
    const int lk = (tid & 3) * 4;

    float acc[4][4];
#pragma unroll
    for (int i = 0; i < 4; ++i)
#pragma unroll
        for (int j = 0; j < 4; ++j) acc[i][j] = 0.f;

    for (int k0 = 0; k0 < K; k0 += KT) {
        {
            const int gm = bm + lm;
            float4 v = make_float4(0.f, 0.f, 0.f, 0.f);
            if (gm < M) v = *reinterpret_cast<const float4*>(A + (size_t)gm * K + k0 + lk);
            As[lk + 0][lm] = v.x; As[lk + 1][lm] = v.y;
            As[lk + 2][lm] = v.z; As[lk + 3][lm] = v.w;
            const int gn = bn + lm;
            float4 u = make_float4(0.f, 0.f, 0.f, 0.f);
            if (gn < N) u = *reinterpret_cast<const float4*>(B + (size_t)gn * K + k0 + lk);
            Bs[lk + 0][lm] = u.x; Bs[lk + 1][lm] = u.y;
            Bs[lk + 2][lm] = u.z; Bs[lk + 3][lm] = u.w;
        }
        __syncthreads();
#pragma unroll
        for (int kk = 0; kk < KT; ++kk) {
            float aa[4], bb[4];
#pragma unroll
            for (int i = 0; i < 4; ++i) aa[i] = As[kk][ty * 4 + i];
#pragma unroll
            for (int j = 0; j < 4; ++j) bb[j] = Bs[kk][tx * 4 + j];
#pragma unroll
            for (int i = 0; i < 4; ++i)
#pragma unroll
                for (int j = 0; j < 4; ++j) acc[i][j] += aa[i] * bb[j];
        }
        __syncthreads();
    }
#pragma unroll
    for (int i = 0; i < 4; ++i) {
        const int gm = bm + ty * 4 + i;
        if (gm >= M) continue;
#pragma unroll
        for (int j = 0; j < 4; ++j) {
            const int gn = bn + tx * 4 + j;
            if (gn >= N) continue;
            float v = alpha * acc[i][j];
            if (bias)  v += biasScale * bias[gn];
            if (resid) v += resid[(size_t)gm * N + gn];
            if (relu)  v = fmaxf(v, 0.f);
            C[(size_t)gm * N + gn] = v;
        }
    }
}

// ---------------------------------------------------------------------------
// LayerNorm variants + small helpers
// ---------------------------------------------------------------------------
__global__ void ln_kernel(const float* __restrict__ X, const float* __restrict__ g,
                          const float* __restrict__ b, float* __restrict__ Y, int M)
{
    const int row = blockIdx.x * 4 + (threadIdx.x >> 6);
    const int lane = threadIdx.x & 63;
    if (row >= M) return;
    const float* x = X + (size_t)row * D_MAIN;
    float v[4]; float s = 0.f;
#pragma unroll
    for (int i = 0; i < 4; ++i) { v[i] = x[lane + 64 * i]; s += v[i]; }
#pragma unroll
    for (int o = 32; o > 0; o >>= 1) s += __shfl_xor(s, o);
    const float mu = s * (1.f / D_MAIN);
    float vs = 0.f;
#pragma unroll
    for (int i = 0; i < 4; ++i) { const float d = v[i] - mu; vs += d * d; }
#pragma unroll
    for (int o = 32; o > 0; o >>= 1) vs += __shfl_xor(vs, o);
    const float inv = rsqrtf(vs * (1.f / D_MAIN) + 1e-5f);
    float* y = Y + (size_t)row * D_MAIN;
#pragma unroll
    for (int i = 0; i < 4; ++i) {
        const int d = lane + 64 * i;
        y[d] = (v[i] - mu) * inv * g[d] + b[d];
    }
}

__global__ void ln_h2h_kernel(const _Float16* __restrict__ X, const float* __restrict__ g,
                              const float* __restrict__ b, _Float16* __restrict__ Y, int M)
{
    const int row = blockIdx.x * 4 + (threadIdx.x >> 6);
    const int lane = threadIdx.x & 63;
    if (row >= M) return;
    const _Float16* x = X + (size_t)row * D_MAIN;
    float v[4]; float s = 0.f;
#pragma unroll
    for (int i = 0; i < 4; ++i) { v[i] = (float)x[lane + 64 * i]; s += v[i]; }
#pragma unroll
    for (int o = 32; o > 0; o >>= 1) s += __shfl_xor(s, o);
    const float mu = s * (1.f / D_MAIN);
    float vs = 0.f;
#pragma unroll
    for (int i = 0; i < 4; ++i) { const float d = v[i] - mu; vs += d * d; }
#pragma unroll
    for (int o = 32; o > 0; o >>= 1) vs += __shfl_xor(vs, o);
    const float inv = rsqrtf(vs * (1.f / D_MAIN) + 1e-5f);
    _Float16* y = Y + (size_t)row * D_MAIN;
#pragma unroll
    for (int i = 0; i < 4; ++i) {
        const int d = lane + 64 * i;
        y[d] = (_Float16)((v[i] - mu) * inv * g[d] + b[d]);
    }
}

// rowsq + sampled-row gather fused
__global__ void rowsq_sample(const float* __restrict__ X, float* __restrict__ sq,
                             const bf* __restrict__ ckh,
                             bf* __restrict__ ckh_s, float* __restrict__ sqc_s, int M)
{
    const int row = blockIdx.x * 4 + (threadIdx.x >> 6);
    const int lane = threadIdx.x & 63;
    if (row >= M) return;
    const float* x = X + (size_t)row * D_MAIN;
    float s = 0.f;
#pragma unroll
    for (int i = 0; i < 4; ++i) { const float v = x[lane + 64 * i]; s += v * v; }
#pragma unroll
    for (int o = 32; o > 0; o >>= 1) s += __shfl_xor(s, o);
    if (lane == 0) sq[row] = s;
    if ((row & 15) == 0) {
        const int r = row >> 4;
        if (r < NS) {
            const bf* srcp = ckh + (size_t)row * D_MAIN;
            bf* dstp = ckh_s + (size_t)r * D_MAIN;
            *(short4*)(dstp + lane * 4) = *(const short4*)(srcp + lane * 4);
            if (lane == 0) sqc_s[r] = s;
        }
    }
}

__global__ void head_kernel(const float* __restrict__ X, const float* __restrict__ g,
                            const float* __restrict__ b, const float* __restrict__ W,
                            const float* __restrict__ bh, float* __restrict__ out, int M)
{
    const int row = blockIdx.x * 4 + (threadIdx.x >> 6);
    const int lane = threadIdx.x & 63;
    if (row >= M) return;
    const float* x = X + (size_t)row * D_MAIN;
    float v[4]; float s = 0.f;
#pragma unroll
    for (int i = 0; i < 4; ++i) { v[i] = x[lane + 64 * i]; s += v[i]; }
#pragma unroll
    for (int o = 32; o > 0; o >>= 1) s += __shfl_xor(s, o);
    const float mu = s * (1.f / D_MAIN);
    float vs = 0.f;
#pragma unroll
    for (int i = 0; i < 4; ++i) { const float d = v[i] - mu; vs += d * d; }
#pragma unroll
    for (int o = 32; o > 0; o >>= 1) vs += __shfl_xor(vs, o);
    const float inv = rsqrtf(vs * (1.f / D_MAIN) + 1e-5f);
    float acc = 0.f;
#pragma unroll
    for (int i = 0; i < 4; ++i) {
        const int d = lane + 64 * i;
        float o_ = (v[i] - mu) * inv * g[d] + b[d];
        o_ = fmaxf(o_, 0.f);
        acc += o_ * W[d];
    }
#pragma unroll
    for (int o = 32; o > 0; o >>= 1) acc += __shfl_xor(acc, o);
    if (lane == 0) out[row] = acc + bh[0];
}

__global__ void f2b_kernel(const float* __restrict__ in, bf* __restrict__ out, int n)
{
    const int i = blockIdx.x * 256 + threadIdx.x;
    if (i < n) out[i] = __float2bfloat16(in[i]);
}

// One-shot conversion of all weights/inputs (7 arrays, one launch).
__global__ void conv_all(
    const float* __restrict__ W_in, const float* __restrict__ W0a,
    const float* __restrict__ W0b, const float* __restrict__ W_k,
    const float* __restrict__ Xtr, const float* __restrict__ W_t1,
    const float* __restrict__ W_t2,
    _Float16* __restrict__ Win16, _Float16* __restrict__ W0a16,
    _Float16* __restrict__ W0b16, _Float16* __restrict__ Wk16,
    _Float16* __restrict__ Xtr16, bf* __restrict__ Wt1b, bf* __restrict__ Wt2b)
{
    const long n1 = D_MAIN * D_IN;
    const long n2 = D_BLOCK * D_MAIN;
    const long n3 = D_MAIN * D_BLOCK;
    const long n4 = D_MAIN * D_MAIN;
    const long n5 = (long)NTRAIN * D_IN;
    const long n6 = D_BLOCK * D_MAIN;
    const long total = n1 + n2 + n3 + n4 + n5 + n6 + (long)D_MAIN * D_BLOCK;
    for (long i = (long)blockIdx.x * 256 + threadIdx.x; i < total;
         i += (long)gridDim.x * 256) {
        long r = i;
        if (r < n1) { Win16[r] = (_Float16)W_in[r]; continue; } r -= n1;
        if (r < n2) { W0a16[r] = (_Float16)W0a[r]; continue; } r -= n2;
        if (r < n3) { W0b16[r] = (_Float16)W0b[r]; continue; } r -= n3;
        if (r < n4) { Wk16[r] = (_Float16)W_k[r]; continue; } r -= n4;
        if (r < n5) { Xtr16[r] = (_Float16)Xtr[r]; continue; } r -= n5;
        if (r < n6) { Wt1b[r] = __float2bfloat16(W_t1[r]); continue; } r -= n6;
        Wt2b[r] = __float2bfloat16(W_t2[r]);
    }
}

// tau[q] = exact TH_RANK-th largest sample score via 4-level radix select.
__global__ __launch_bounds__(256) void thresh_kernel(
    const float* __restrict__ ss, float* __restrict__ tau)
{
    const int q = blockIdx.x, tid = threadIdx.x;
    __shared__ union {
        unsigned h12[2][4096];
        struct { unsigned h8[4][256]; unsigned A[2048]; unsigned B[2048]; } r;
    } u;
    __shared__ unsigned cs[256];
    __shared__ int sh_bin, sh_need, cc;

    for (int i = tid; i < 8192; i += 256) ((unsigned*)u.h12)[i] = 0;
    __syncthreads();
    const int rep2 = (tid >> 7) & 1;
    for (int i = tid; i < NS; i += 256) {
        const unsigned uu = __float_as_uint(ss[(size_t)q * NS + i]);
        const unsigned key = (uu & 0x80000000u) ? ~uu : (uu | 0x80000000u);
        atomicAdd(&u.h12[rep2][key >> 20], 1u);
    }
    __syncthreads();
    unsigned s = 0;
    for (int b = tid * 16; b < tid * 16 + 16; ++b) s += u.h12[0][b] + u.h12[1][b];
    cs[tid] = s;
    __syncthreads();
    if (tid == 0) {
        unsigned cum = 0; int g = 255;
        for (; g > 0; --g) {
            if (cum + cs[g] >= (unsigned)TH_RANK) break;
            cum += cs[g];
        }
        int b = g * 16;
        for (int bb = g * 16 + 15; bb >= g * 16; --bb) {
            const unsigned c = u.h12[0][bb] + u.h12[1][bb];
            if (cum + c >= (unsigned)TH_RANK) { b = bb; break; }
            cum += c;
        }
        sh_bin = b; sh_need = TH_RANK - (int)cum; cc = 0;
    }
    __syncthreads();
    const unsigned bin12 = (unsigned)sh_bin;
    for (int i = tid; i < NS; i += 256) {
        const unsigned uu = __float_as_uint(ss[(size_t)q * NS + i]);
        const unsigned key = (uu & 0x80000000u) ? ~uu : (uu | 0x80000000u);
        if ((key >> 20) == bin12) {
            const int p = atomicAdd(&cc, 1);
            if (p < 2048) u.r.A[p] = key;
        }
    }
    __syncthreads();
    int E = cc < 2048 ? cc : 2048;
    unsigned* src = u.r.A;
    unsigned* dst = u.r.B;
    const int rep4 = tid >> 6;
    for (int lvl = 0; lvl < 3; ++lvl) {
        const int sh = (lvl == 0) ? 12 : (lvl == 1) ? 4 : 0;
        const unsigned msk = (lvl == 2) ? 15u : 255u;
        const int nb = (lvl == 2) ? 16 : 256;
        for (int i = tid; i < 1024; i += 256) ((unsigned*)u.r.h8)[i] = 0;
        if (tid == 0) cc = 0;
        __syncthreads();
        for (int e = tid; e < E; e += 256) atomicAdd(&u.r.h8[rep4][(src[e] >> sh) & msk], 1u);
        __syncthreads();
        if (tid == 0) {
            const int need = sh_need;
            unsigned cum = 0; int b = nb - 1;
            for (; b > 0; --b) {
                const unsigned c = u.r.h8[0][b] + u.r.h8[1][b] + u.r.h8[2][b] + u.r.h8[3][b];
                if (cum + c >= (unsigned)need) break;
                cum += c;
            }
            sh_bin = b; sh_need = need - (int)cum;
        }
        __syncthreads();
        const unsigned b = (unsigned)sh_bin;
        for (int e = tid; e < E; e += 256) {
            if (((src[e] >> sh) & msk) == b) {
                const int p = atomicAdd(&cc, 1);
                if (p < 2048) dst[p] = src[e];
            }
        }
        __syncthreads();
        E = cc < 2048 ? cc : 2048;
        unsigned* t = src; src = dst; dst = t;
        __syncthreads();
    }
    if (tid == 0) {
        const unsigned key = src[0];
        const unsigned uu = (key & 0x80000000u) ? (key & 0x7fffffffu) : ~key;
        tau[q] = __uint_as_float(uu);
    }
}

// per chunk-local query: gather candidates from transposed (cnt2, pool) cells,
// then top-128 by (score desc, col asc) via bitonic over dynamic pow-2 size.
__global__ __launch_bounds__(256) void select_kernel(
    const u64* __restrict__ pool, const int* __restrict__ cnt2,
    int* __restrict__ idx128, int nN, int q0, int Mrows)
{
    const int q = blockIdx.x, tid = threadIdx.x;
    __shared__ u64 k[CAND_CAP];
    __shared__ int lc;
    if (tid == 0) lc = 0;
    __syncthreads();
    for (int t = tid; t < nN; t += 256) {
        const size_t cell = (size_t)t * Mrows + q;
        const int c = cnt2[cell];
        const u64* src = pool + cell * SLOTS;
        for (int s = 0; s < c; ++s) {
            const int p = atomicAdd(&lc, 1);
            if (p < CAND_CAP) k[p] = src[s];
        }
    }
    __syncthreads();
    int E = lc; if (E > CAND_CAP) E = CAND_CAP;
    int P = K_PRE; while (P < E) P <<= 1;
    for (int i = tid; i < P; i += 256)
        if (i >= E) k[i] = ~0ull;
    __syncthreads();
    for (int kk = 2; kk <= P; kk <<= 1) {
        for (int j = kk >> 1; j > 0; j >>= 1) {
            for (int i = tid; i < P; i += 256) {
                const int ixj = i ^ j;
                if (ixj > i) {
                    const bool up = ((i & kk) == 0);
                    const u64 a = k[i], b2 = k[ixj];
                    if ((a > b2) == up) { k[i] = b2; k[ixj] = a; }
                }
            }
            __syncthreads();
        }
    }
    if (tid < K_PRE) {
        const u64 e = (tid < E) ? k[tid] : k[0];
        idx128[(size_t)(q0 + q) * K_PRE + tid] = (int)(e & 0xffffffffu);
    }
}

// ---------------------------------------------------------------------------
// Exact re-rank + fused diff write: fp32 d2 over 128 candidates, top-96 with
// (d2, idx) tie rule, sims out; then writes bf16 diff rows for the 96 winners.
// ---------------------------------------------------------------------------
__global__ __launch_bounds__(256) void rerank_kernel(
    const float* __restrict__ k_q, const float* __restrict__ ck,
    const int* __restrict__ idx128, int* __restrict__ idx96,
    float* __restrict__ sims96, bf* __restrict__ diff)
{
    const int q = blockIdx.x;
    const int tid = threadIdx.x;
    const int w = tid >> 6, lam = tid & 63;
    __shared__ float kq[D_MAIN];
    __shared__ u64 keys[K_PRE];
    kq[tid] = k_q[(size_t)q * D_MAIN + tid];
    __syncthreads();

    for (int c = w * 32; c < w * 32 + 32; ++c) {
        const int j = idx128[(size_t)q * K_PRE + c];
        const float4 cv = *(const float4*)(ck + (size_t)j * D_MAIN + lam * 4);
        const float d0 = kq[lam * 4 + 0] - cv.x;
        const float d1 = kq[lam * 4 + 1] - cv.y;
        const float d2_ = kq[lam * 4 + 2] - cv.z;
        const float d3 = kq[lam * 4 + 3] - cv.w;
        float s = d0 * d0 + d1 * d1 + d2_ * d2_ + d3 * d3;
#pragma unroll
        for (int o = 32; o > 0; o >>= 1) s += __shfl_xor(s, o);
        if (lam == 0)
            keys[c] = ((u64)__float_as_uint(s) << 32) | (unsigned)j;
    }
    __syncthreads();

    for (int k = 2; k <= K_PRE; k <<= 1) {
        for (int j = k >> 1; j > 0; j >>= 1) {
            if (tid < K_PRE) {
                const int ixj = tid ^ j;
                if (ixj > tid) {
                    const bool up = ((tid & k) == 0);
                    const u64 a = keys[tid], b2 = keys[ixj];
                    if ((a > b2) == up) { keys[tid] = b2; keys[ixj] = a; }
                }
            }
            __syncthreads();
        }
    }
    u64 k2 = ~0ull;
    if (tid < CTX) k2 = (keys[tid] << 32) | (keys[tid] >> 32);
    __syncthreads();
    if (tid < K_PRE) keys[tid] = k2;
    __syncthreads();
    for (int k = 2; k <= K_PRE; k <<= 1) {
        for (int j = k >> 1; j > 0; j >>= 1) {
            if (tid < K_PRE) {
                const int ixj = tid ^ j;
                if (ixj > tid) {
                    const bool up = ((tid & k) == 0);
                    const u64 a = keys[tid], b2 = keys[ixj];
                    if ((a > b2) == up) { keys[tid] = b2; keys[ixj] = a; }
                }
            }
            __syncthreads();
        }
    }
    if (tid < CTX) {
        idx96[(size_t)q * CTX + tid] = (int)(keys[tid] >> 32);
        sims96[(size_t)q * CTX + tid] = -__uint_as_float((unsigned)(keys[tid] & 0xffffffffu));
    }
    __syncthreads();
    for (int c = w; c < CTX; c += 4) {
        const int j = (int)(keys[c] >> 32);
        const float4 cv = *(const float4*)(ck + (size_t)j * D_MAIN + lam * 4);
        bf tmp[4];
        tmp[0] = __float2bfloat16(kq[lam * 4 + 0] - cv.x);
        tmp[1] = __float2bfloat16(kq[lam * 4 + 1] - cv.y);
        tmp[2] = __float2bfloat16(kq[lam * 4 + 2] - cv.z);
        tmp[3] = __float2bfloat16(kq[lam * 4 + 3] - cv.w);
        bf* drow = diff + ((size_t)q * CTX + c) * D_MAIN + lam * 4;
        *(short4*)drow = *(short4*)tmp;
    }
}

__global__ void combine_kernel(const float* __restrict__ sscA, const int* __restrict__ idxA,
                               const float* __restrict__ ytr, const float* __restrict__ w_lab,
                               const float* __restrict__ b_lab, const bf* __restrict__ vv,
                               float* __restrict__ x_q, int q0)
{
    const int q = q0 + blockIdx.x;
    __shared__ float pr[CTX];
    __shared__ float sh_ybar;
    const int tid = threadIdx.x;
    if (tid == 0) {
        float mx = -1e30f;
        for (int c = 0; c < CTX; ++c) mx = fmaxf(mx, sscA[(size_t)q * CTX + c]);
        float sum = 0.f;
        for (int c = 0; c < CTX; ++c) {
            const float e = __expf(sscA[(size_t)q * CTX + c] - mx);
            pr[c] = e; sum += e;
        }
        const float inv = 1.f / sum;
        float yb = 0.f;
        for (int c = 0; c < CTX; ++c) {
            pr[c] *= inv;
            yb += pr[c] * ytr[idxA[(size_t)q * CTX + c]];
        }
        sh_ybar = yb;
    }
    __syncthreads();
    const int d = tid;
    float acc = 0.f;
    const bf* vq = vv + (size_t)blockIdx.x * CTX * D_MAIN;
    for (int c = 0; c < CTX; ++c) acc += pr[c] * __bfloat162float(vq[(size_t)c * D_MAIN + d]);
    x_q[(size_t)q * D_MAIN + d] += acc + sh_ybar * w_lab[d] + b_lab[d];
}

// ---------------------------------------------------------------------------
extern "C" void kernel_launch(void* const* d_in, const int* in_sizes, int n_in,
                              void* d_out, int out_size, void* d_ws, size_t ws_size,
                              hipStream_t stream)
{
    const float* X      = (const float*)d_in[0];
    const float* Xtr    = (const float*)d_in[1];
    const float* ytr    = (const float*)d_in[2];
    const float* W_in   = (const float*)d_in[3];
    const float* b_in   = (const float*)d_in[4];
    const float* W0a    = (const float*)d_in[5];
    const float* b0a    = (const float*)d_in[6];
    const float* W0b    = (const float*)d_in[7];
    const float* b0b    = (const float*)d_in[8];
    const float* g_mix  = (const float*)d_in[9];
    const float* be_mix = (const float*)d_in[10];
    const float* W_k    = (const float*)d_in[11];
    const float* b_k    = (const float*)d_in[12];
    const float* w_lab  = (const float*)d_in[13];
    const float* b_lab  = (const float*)d_in[14];
    const float* W_t1   = (const float*)d_in[15];
    const float* b_t1   = (const float*)d_in[16];
    const float* W_t2   = (const float*)d_in[17];
    const float* g_p    = (const float*)d_in[18];
    const float* be_p   = (const float*)d_in[19];
    const float* W1a    = (const float*)d_in[20];
    const float* b1a    = (const float*)d_in[21];
    const float* W1b    = (const float*)d_in[22];
    const float* b1b    = (const float*)d_in[23];
    const float* g_h    = (const float*)d_in[24];
    const float* be_h   = (const float*)d_in[25];
    const float* W_h    = (const float*)d_in[26];
    const float* b_h    = (const float*)d_in[27];
    float* out = (float*)d_out;

    char* ws = (char*)d_ws;
    size_t off = 0;
    auto alloc = [&](size_t bytes) -> void* {
        void* p = ws + off;
        off += (bytes + 255) & ~(size_t)255;
        return p;
    };
    float*     ck    = (float*)alloc((size_t)NTRAIN * D_MAIN * 4);
    bf*        ckh   = (bf*)   alloc((size_t)NTRAIN * D_MAIN * 2);
    float*     sqc   = (float*)alloc((size_t)NTRAIN * 4);
    _Float16*  Xtr16 = (_Float16*)alloc((size_t)NTRAIN * D_IN * 2);
    _Float16*  Win16 = (_Float16*)alloc((size_t)D_MAIN * D_IN * 2);
    _Float16*  W0a16 = (_Float16*)alloc((size_t)D_BLOCK * D_MAIN * 2);
    _Float16*  W0b16 = (_Float16*)alloc((size_t)D_MAIN * D_BLOCK * 2);
    _Float16*  Wk16  = (_Float16*)alloc((size_t)D_MAIN * D_MAIN * 2);
    bf*        Wt1b  = (bf*)   alloc((size_t)D_BLOCK * D_MAIN * 2);
    bf*        Wt2b  = (bf*)   alloc((size_t)D_MAIN * D_BLOCK * 2);
    float*     x_q   = (float*)alloc((size_t)NQ * D_MAIN * 4);
    float*     h_q   = (float*)alloc((size_t)NQ * D_MAIN * 4);
    float*     t_q   = (float*)alloc((size_t)NQ * D_BLOCK * 4);
    float*     ln_q  = (float*)alloc((size_t)NQ * D_MAIN * 4);
    float*     k_q   = (float*)alloc((size_t)NQ * D_MAIN * 4);
    bf*        k_qb  = (bf*)   alloc((size_t)NQ * D_MAIN * 2);
    int*       idx128 = (int*) alloc((size_t)NQ * K_PRE * 4);
    int*       idxA  = (int*)  alloc((size_t)NQ * CTX * 4);
    float*     sscA  = (float*)alloc((size_t)NQ * CTX * 4);
    bf*        ckh_s = (bf*)   alloc((size_t)NS * D_MAIN * 2);
    float*     sqc_s = (float*)alloc((size_t)NS * 4);
    float*     tauA  = (float*)alloc((size_t)NQ * 4);

    const size_t bigOff = off;
    const size_t bigBytes = (ws_size > bigOff) ? (ws_size - bigOff) : 0;
    char* big = ws + bigOff;

    // one-shot conversions
    conv_all<<<2048, 256, 0, stream>>>(W_in, W0a, W0b, W_k, Xtr, W_t1, W_t2,
        Win16, W0a16, W0b16, Wk16, Xtr16, Wt1b, Wt2b);

    // ---------------- encode queries (fp32 exact) ----------------
    {
        dim3 g1((D_MAIN + TILE - 1) / TILE, (NQ + TILE - 1) / TILE);
        gemm_bias_act<<<g1, 256, 0, stream>>>(X, W_in, b_in, 1.f, nullptr, h_q, NQ, D_MAIN, D_IN, 1.f, 0);
        dim3 g2((D_BLOCK + TILE - 1) / TILE, (NQ + TILE - 1) / TILE);
        gemm_bias_act<<<g2, 256, 0, stream>>>(h_q, W0a, b0a, 1.f, nullptr, t_q, NQ, D_BLOCK, D_MAIN, 1.f, 1);
        gemm_bias_act<<<g1, 256, 0, stream>>>(t_q, W0b, b0b, 1.f, h_q, x_q, NQ, D_MAIN, D_BLOCK, 1.f, 0);
        ln_kernel<<<(NQ + 3) / 4, 256, 0, stream>>>(x_q, g_mix, be_mix, ln_q, NQ);
        gemm_bias_act<<<g1, 256, 0, stream>>>(ln_q, W_k, b_k, 1.f, nullptr, k_q, NQ, D_MAIN, D_MAIN, 1.f, 0);
        f2b_kernel<<<(NQ * D_MAIN + 255) / 256, 256, 0, stream>>>(k_q, k_qb, NQ * D_MAIN);
    }

    // ---------------- encode train (fp16 MFMA, in-place x; 1.5KB/row) -------
    {
        long Rmax = (long)(bigBytes / 1536);
        int R = (int)(Rmax < 100096 ? Rmax : 100096);
        R &= ~127;
        if (R < 128) R = 128;
        _Float16* h16  = (_Float16*)big;                       // R*512 B (x in-place)
        _Float16* t16  = (_Float16*)(big + (size_t)R * 512);   // R*1024 B
        _Float16* ln16 = t16;                                  // alias (t dead after W0b)
        for (int r0 = 0; r0 < NTRAIN; r0 += R) {
            const int Rc = (NTRAIN - r0 < R) ? (NTRAIN - r0) : R;
            dim3 gA(2, (Rc + 127) / 128);
            dim3 gB(4, (Rc + 127) / 128);
            gemm_fp16<<<gA, 256, 0, stream>>>(Xtr16 + (size_t)r0 * D_IN, Win16,
                Rc, D_MAIN, D_IN, b_in, nullptr, nullptr, h16, nullptr, 0);
            gemm_fp16<<<gB, 256, 0, stream>>>(h16, W0a16, Rc, D_BLOCK, D_MAIN,
                b0a, nullptr, nullptr, t16, nullptr, 1);
            gemm_fp16<<<gA, 256, 0, stream>>>(t16, W0b16, Rc, D_MAIN, D_BLOCK,
                b0b, h16, nullptr, h16, nullptr, 0);
            ln_h2h_kernel<<<(Rc + 3) / 4, 256, 0, stream>>>(h16, g_mix, be_mix, ln16, Rc);
            gemm_fp16<<<gA, 256, 0, stream>>>(ln16, Wk16, Rc, D_MAIN, D_MAIN,
                b_k, nullptr, ck + (size_t)r0 * D_MAIN, nullptr,
                ckh + (size_t)r0 * D_MAIN, 0);
        }
    }
    rowsq_sample<<<(NTRAIN + 3) / 4, 256, 0, stream>>>(ck, sqc, ckh, ckh_s, sqc_s, NTRAIN);

    // ---------------- phase A: sampled-threshold selection (atomic-free) -----
    {
        float* scores_s = (float*)big;      // 25.6 MB; dead after thresh
        dim3 gss((NS + 127) / 128, (NQ + 127) / 128);
        gemm_bf16<<<gss, 256, 0, stream>>>(k_qb, ckh_s, NQ, NS, D_MAIN,
            2.f, sqc_s, -1.f, scores_s, nullptr, 0);
        thresh_kernel<<<NQ, 256, 0, stream>>>(scores_s, tauA);

        const int nN = (NTRAIN + 127) / 128;          // 782 N-tiles
        const size_t perRow = (size_t)nN * SLOTS * 8 + (size_t)nN * 4 + 256;
        int Qc = 256, mshift = 0;
        while (Qc < NQ && (size_t)(Qc * 2) * perRow <= bigBytes) { Qc <<= 1; ++mshift; }
        const int nGroups = (nN + 7) / 8;
        for (int q0 = 0; q0 < NQ; q0 += Qc) {
            u64* pool = (u64*)big;                    // reuses scores_s space
            int* cnt2 = (int*)(big + (size_t)Qc * nN * SLOTS * 8);
            gemm_bf16_filter<<<nGroups * 8 * (1 << mshift), 256, 0, stream>>>(
                k_qb + (size_t)q0 * D_MAIN, ckh, Qc, NTRAIN, D_MAIN,
                2.f, sqc, -1.f, tauA + q0, pool, cnt2, nN, mshift);
            select_kernel<<<Qc, 256, 0, stream>>>(pool, cnt2, idx128, nN, q0, Qc);
        }
    }

    // ---------------- phase B: exact re-rank + fused diff write --------------
    const size_t diffBytes = ((size_t)NQ * CTX * D_MAIN * 2 + 255) & ~(size_t)255;
    bf* diffAll = (bf*)big;
    rerank_kernel<<<NQ, 256, 0, stream>>>(k_q, ck, idx128, idxA, sscA, diffAll);

    // ---------------- phase C: values MLP + combine (chunked) ----------------
    {
        char* cbase = big + diffBytes;
        const size_t cBytes = (bigBytes > diffBytes) ? (bigBytes - diffBytes) : 0;
        const size_t perQ = (size_t)CTX * (D_BLOCK * 2 + D_MAIN * 2); // tt + vvh
        long Qmax = (long)(cBytes / perQ);
        int Q = (int)(Qmax < NQ ? Qmax : NQ);
        if (Q < 1) Q = 1;
        for (int q0 = 0; q0 < NQ; q0 += Q) {
            const int Qc = (NQ - q0 < Q) ? (NQ - q0) : Q;
            bf* tt  = (bf*)cbase;
            bf* vvh = (bf*)(cbase + (size_t)Qc * CTX * D_BLOCK * 2);
            dim3 g1((D_BLOCK + 127) / 128, (Qc * CTX + 127) / 128);
            gemm_bf16<<<g1, 256, 0, stream>>>(diffAll + (size_t)q0 * CTX * D_MAIN, Wt1b,
                Qc * CTX, D_BLOCK, D_MAIN, 1.f, b_t1, 1.f, nullptr, tt, 1);
            dim3 g2((D_MAIN + 127) / 128, (Qc * CTX + 127) / 128);
            gemm_bf16<<<g2, 256, 0, stream>>>(tt, Wt2b, Qc * CTX, D_MAIN, D_BLOCK,
                1.f, nullptr, 0.f, nullptr, vvh, 0);
            combine_kernel<<<Qc, 256, 0, stream>>>(sscA, idxA, ytr, w_lab, b_lab, vvh, x_q, q0);
        }
    }

    // ---------------- predictor + head (fp32 exact) ----------------
    {
        dim3 g1((D_MAIN + TILE - 1) / TILE, (NQ + TILE - 1) / TILE);
        dim3 g2((D_BLOCK + TILE - 1) / TILE, (NQ + TILE - 1) / TILE);
        ln_kernel<<<(NQ + 3) / 4, 256, 0, stream>>>(x_q, g_p, be_p, ln_q, NQ);
        gemm_bias_act<<<g2, 256, 0, stream>>>(ln_q, W1a, b1a, 1.f, nullptr, t_q, NQ, D_BLOCK, D_MAIN, 1.f, 1);
        gemm_bias_act<<<g1, 256, 0, stream>>>(t_q, W1b, b1b, 1.f, x_q, x_q, NQ, D_MAIN, D_BLOCK, 1.f, 0);
        head_kernel<<<(NQ + 3) / 4, 256, 0, stream>>>(x_q, g_h, be_h, W_h, b_h, out, NQ);
    }
}

// Round 16
// 1177.063 us; speedup vs baseline: 1.1447x; 1.1447x over previous
//
#include <hip/hip_runtime.h>
#include <hip/hip_bf16.h>
#include <cstdint>
#include <cstddef>

#define D_IN    32
#define D_MAIN  256
#define D_BLOCK 512
#define CTX     96
#define K_PRE   128
#define NQ      1024
#define NTRAIN  100000
#define NS      6250      // sampled candidates (stride 16)
#define TH_RANK 48        // sample rank for threshold -> ~768 expected candidates
#define CAND_CAP 2048
#define SLOTS   12        // per (row, 128-col tile) candidate slots

typedef __attribute__((ext_vector_type(8))) short bf16x8;
typedef __attribute__((ext_vector_type(8))) _Float16 f16x8;
typedef __attribute__((ext_vector_type(4))) float f32x4;
typedef __hip_bfloat16 bf;
typedef unsigned long long u64;

#define GLL(gp, lp) __builtin_amdgcn_global_load_lds( \
    (const __attribute__((address_space(1))) void*)(gp), \
    (__attribute__((address_space(3))) void*)(lp), 16, 0, 0)

// ---------------------------------------------------------------------------
// Plain bf16 MFMA GEMM: C = act(alpha*(A@B^T) + biasScale*bias[n])
// 128x128 tile, BK=32, 4 waves, 16x16x32 MFMA, XOR-swizzled LDS staging.
// ---------------------------------------------------------------------------
__global__ __launch_bounds__(256) void gemm_bf16(
    const bf* __restrict__ A, const bf* __restrict__ B,
    int M, int N, int K, float alpha,
    const float* __restrict__ bias, float biasScale,
    float* __restrict__ Cf, bf* __restrict__ Ch, int relu)
{
    __shared__ __align__(16) char smem[16384];
    const int tid = threadIdx.x;
    const int w   = tid >> 6;
    const int lam = tid & 63;
    const int bm  = blockIdx.y * 128;
    const int bn  = blockIdx.x * 128;
    const int wm  = w >> 1, wn = w & 1;

    f32x4 acc[4][4];
#pragma unroll
    for (int i = 0; i < 4; ++i)
#pragma unroll
        for (int j = 0; j < 4; ++j) acc[i][j] = (f32x4){0.f, 0.f, 0.f, 0.f};

    const int r0s  = w * 16 + (lam >> 2);
    const int slot = lam & 3;
    const int g0   = slot ^ ((r0s >> 1) & 3);
    const int g1   = slot ^ (((r0s + 64) >> 1) & 3);
    const size_t strideAB = (size_t)K * 2;
    long ga0 = bm + r0s;      if (ga0 >= M) ga0 = M - 1;
    long ga1 = bm + r0s + 64; if (ga1 >= M) ga1 = M - 1;
    long gb0 = bn + r0s;      if (gb0 >= N) gb0 = N - 1;
    long gb1 = bn + r0s + 64; if (gb1 >= N) gb1 = N - 1;
    const char* pa0 = (const char*)A + (size_t)ga0 * strideAB + 16 * g0;
    const char* pa1 = (const char*)A + (size_t)ga1 * strideAB + 16 * g1;
    const char* pb0 = (const char*)B + (size_t)gb0 * strideAB + 16 * g0;
    const char* pb1 = (const char*)B + (size_t)gb1 * strideAB + 16 * g1;

    const int sread = (lam >> 4) ^ ((lam >> 1) & 3);
    const int abase = wm * 4096 + (lam & 15) * 64 + sread * 16;
    const int bbase = 8192 + wn * 4096 + (lam & 15) * 64 + sread * 16;

    for (int k0 = 0; k0 < K; k0 += 32) {
        __syncthreads();
        const size_t kb = 2 * (size_t)k0;
        GLL(pa0 + kb, smem + w * 1024);
        GLL(pa1 + kb, smem + 4096 + w * 1024);
        GLL(pb0 + kb, smem + 8192 + w * 1024);
        GLL(pb1 + kb, smem + 12288 + w * 1024);
        asm volatile("s_waitcnt vmcnt(0)" ::: "memory");
        __syncthreads();

        bf16x8 aF[4], bF[4];
#pragma unroll
        for (int i = 0; i < 4; ++i) aF[i] = *(const bf16x8*)(smem + abase + 1024 * i);
#pragma unroll
        for (int j = 0; j < 4; ++j) bF[j] = *(const bf16x8*)(smem + bbase + 1024 * j);
#pragma unroll
        for (int i = 0; i < 4; ++i)
#pragma unroll
            for (int j = 0; j < 4; ++j)
                acc[i][j] = __builtin_amdgcn_mfma_f32_16x16x32_bf16(aF[i], bF[j], acc[i][j], 0, 0, 0);
    }

    const int col0 = bn + wn * 64 + (lam & 15);
    const int row0 = bm + wm * 64 + ((lam >> 4) << 2);
#pragma unroll
    for (int j = 0; j < 4; ++j) {
        const int col = col0 + 16 * j;
        if (col >= N) continue;
        const float bv = bias ? biasScale * bias[col] : 0.f;
#pragma unroll
        for (int i = 0; i < 4; ++i) {
#pragma unroll
            for (int r = 0; r < 4; ++r) {
                const int row = row0 + 16 * i + r;
                if (row >= M) continue;
                float v = alpha * acc[i][j][r] + bv;
                if (relu) v = fmaxf(v, 0.f);
                const size_t idx = (size_t)row * N + col;
                if (Cf) Cf[idx] = v;
                if (Ch) Ch[idx] = __float2bfloat16(v);
            }
        }
    }
}

// ---------------------------------------------------------------------------
// Plain fp16 MFMA GEMM (train encoder): C = act(A@B^T + bias[n] (+ res16))
// Outputs: fp32 / fp16 / bf16 (any subset). res16 may alias Ch (same-index
// read-then-write within one thread).
// ---------------------------------------------------------------------------
__global__ __launch_bounds__(256) void gemm_fp16(
    const _Float16* __restrict__ A, const _Float16* __restrict__ B,
    int M, int N, int K,
    const float* __restrict__ bias, const _Float16* res16,
    float* __restrict__ Cf, _Float16* Ch, bf* __restrict__ Cb,
    int relu)
{
    __shared__ __align__(16) char smem[16384];
    const int tid = threadIdx.x;
    const int w   = tid >> 6;
    const int lam = tid & 63;
    const int bm  = blockIdx.y * 128;
    const int bn  = blockIdx.x * 128;
    const int wm  = w >> 1, wn = w & 1;

    f32x4 acc[4][4];
#pragma unroll
    for (int i = 0; i < 4; ++i)
#pragma unroll
        for (int j = 0; j < 4; ++j) acc[i][j] = (f32x4){0.f, 0.f, 0.f, 0.f};

    const int r0s  = w * 16 + (lam >> 2);
    const int slot = lam & 3;
    const int g0   = slot ^ ((r0s >> 1) & 3);
    const int g1   = slot ^ (((r0s + 64) >> 1) & 3);
    const size_t strideAB = (size_t)K * 2;
    long ga0 = bm + r0s;      if (ga0 >= M) ga0 = M - 1;
    long ga1 = bm + r0s + 64; if (ga1 >= M) ga1 = M - 1;
    long gb0 = bn + r0s;      if (gb0 >= N) gb0 = N - 1;
    long gb1 = bn + r0s + 64; if (gb1 >= N) gb1 = N - 1;
    const char* pa0 = (const char*)A + (size_t)ga0 * strideAB + 16 * g0;
    const char* pa1 = (const char*)A + (size_t)ga1 * strideAB + 16 * g1;
    const char* pb0 = (const char*)B + (size_t)gb0 * strideAB + 16 * g0;
    const char* pb1 = (const char*)B + (size_t)gb1 * strideAB + 16 * g1;

    const int sread = (lam >> 4) ^ ((lam >> 1) & 3);
    const int abase = wm * 4096 + (lam & 15) * 64 + sread * 16;
    const int bbase = 8192 + wn * 4096 + (lam & 15) * 64 + sread * 16;

    for (int k0 = 0; k0 < K; k0 += 32) {
        __syncthreads();
        const size_t kb = 2 * (size_t)k0;
        GLL(pa0 + kb, smem + w * 1024);
        GLL(pa1 + kb, smem + 4096 + w * 1024);
        GLL(pb0 + kb, smem + 8192 + w * 1024);
        GLL(pb1 + kb, smem + 12288 + w * 1024);
        asm volatile("s_waitcnt vmcnt(0)" ::: "memory");
        __syncthreads();

        f16x8 aF[4], bF[4];
#pragma unroll
        for (int i = 0; i < 4; ++i) aF[i] = *(const f16x8*)(smem + abase + 1024 * i);
#pragma unroll
        for (int j = 0; j < 4; ++j) bF[j] = *(const f16x8*)(smem + bbase + 1024 * j);
#pragma unroll
        for (int i = 0; i < 4; ++i)
#pragma unroll
            for (int j = 0; j < 4; ++j)
                acc[i][j] = __builtin_amdgcn_mfma_f32_16x16x32_f16(aF[i], bF[j], acc[i][j], 0, 0, 0);
    }

    const int col0 = bn + wn * 64 + (lam & 15);
    const int row0 = bm + wm * 64 + ((lam >> 4) << 2);
#pragma unroll
    for (int j = 0; j < 4; ++j) {
        const int col = col0 + 16 * j;
        if (col >= N) continue;
        const float bv = bias ? bias[col] : 0.f;
#pragma unroll
        for (int i = 0; i < 4; ++i) {
#pragma unroll
            for (int r = 0; r < 4; ++r) {
                const int row = row0 + 16 * i + r;
                if (row >= M) continue;
                float v = acc[i][j][r] + bv;
                const size_t idx = (size_t)row * N + col;
                if (res16) v += (float)res16[idx];
                if (relu) v = fmaxf(v, 0.f);
                if (Cf) Cf[idx] = v;
                if (Ch) Ch[idx] = (_Float16)v;
                if (Cb) Cb[idx] = __float2bfloat16(v);
            }
        }
    }
}

// ---------------------------------------------------------------------------
// Filter GEMM (Round-14 config: BM=128) over a chunk of Mrows query rows.
// XCD-pinned 1D grid: b -> nl=b&7, mt=(b>>3)&(mtiles-1), nt=(b>>(3+mshift))*8+nl.
// ATOMIC-FREE epilogue, COALESCED cells (nt*Mrows + row).
// ---------------------------------------------------------------------------
__global__ __launch_bounds__(256) void gemm_bf16_filter(
    const bf* __restrict__ A, const bf* __restrict__ B,
    int Mrows, int N, int K, float alpha,
    const float* __restrict__ bias, float biasScale,
    const float* __restrict__ tau,
    u64* __restrict__ pool, int* __restrict__ cnt2, int nN, int mshift)
{
    __shared__ __align__(16) char smem[16384];
    __shared__ int lcnt[128];
    __shared__ float stau[128];
    __shared__ u64 lcand[128][SLOTS];
    const int bidx = blockIdx.x;
    const int nl = bidx & 7;
    const int mt = (bidx >> 3) & ((1 << mshift) - 1);
    const int nt = (bidx >> (3 + mshift)) * 8 + nl;
    if (nt >= nN) return;
    const int bm = mt * 128;
    const int bn = nt * 128;

    const int tid = threadIdx.x;
    const int w   = tid >> 6;
    const int lam = tid & 63;
    const int wm  = w >> 1, wn = w & 1;

    if (tid < 128) { lcnt[tid] = 0; stau[tid] = tau[bm + tid]; }

    f32x4 acc[4][4];
#pragma unroll
    for (int i = 0; i < 4; ++i)
#pragma unroll
        for (int j = 0; j < 4; ++j) acc[i][j] = (f32x4){0.f, 0.f, 0.f, 0.f};

    const int r0s  = w * 16 + (lam >> 2);
    const int slot = lam & 3;
    const int g0   = slot ^ ((r0s >> 1) & 3);
    const int g1   = slot ^ (((r0s + 64) >> 1) & 3);
    const size_t strideAB = (size_t)K * 2;
    long ga0 = bm + r0s;      if (ga0 >= Mrows) ga0 = Mrows - 1;
    long ga1 = bm + r0s + 64; if (ga1 >= Mrows) ga1 = Mrows - 1;
    long gb0 = bn + r0s;      if (gb0 >= N) gb0 = N - 1;
    long gb1 = bn + r0s + 64; if (gb1 >= N) gb1 = N - 1;
    const char* pa0 = (const char*)A + (size_t)ga0 * strideAB + 16 * g0;
    const char* pa1 = (const char*)A + (size_t)ga1 * strideAB + 16 * g1;
    const char* pb0 = (const char*)B + (size_t)gb0 * strideAB + 16 * g0;
    const char* pb1 = (const char*)B + (size_t)gb1 * strideAB + 16 * g1;

    const int sread = (lam >> 4) ^ ((lam >> 1) & 3);
    const int abase = wm * 4096 + (lam & 15) * 64 + sread * 16;
    const int bbase = 8192 + wn * 4096 + (lam & 15) * 64 + sread * 16;

    for (int k0 = 0; k0 < K; k0 += 32) {
        __syncthreads();
        const size_t kb = 2 * (size_t)k0;
        GLL(pa0 + kb, smem + w * 1024);
        GLL(pa1 + kb, smem + 4096 + w * 1024);
        GLL(pb0 + kb, smem + 8192 + w * 1024);
        GLL(pb1 + kb, smem + 12288 + w * 1024);
        asm volatile("s_waitcnt vmcnt(0)" ::: "memory");
        __syncthreads();

        bf16x8 aF[4], bF[4];
#pragma unroll
        for (int i = 0; i < 4; ++i) aF[i] = *(const bf16x8*)(smem + abase + 1024 * i);
#pragma unroll
        for (int j = 0; j < 4; ++j) bF[j] = *(const bf16x8*)(smem + bbase + 1024 * j);
#pragma unroll
        for (int i = 0; i < 4; ++i)
#pragma unroll
            for (int j = 0; j < 4; ++j)
                acc[i][j] = __builtin_amdgcn_mfma_f32_16x16x32_bf16(aF[i], bF[j], acc[i][j], 0, 0, 0);
    }

    const int col0 = bn + wn * 64 + (lam & 15);
    const int lrow0 = wm * 64 + ((lam >> 4) << 2);
#pragma unroll
    for (int j = 0; j < 4; ++j) {
        const int col = col0 + 16 * j;
        if (col >= N) continue;
        const float bv = biasScale * bias[col];
#pragma unroll
        for (int i = 0; i < 4; ++i) {
#pragma unroll
            for (int r = 0; r < 4; ++r) {
                const int lrow = lrow0 + 16 * i + r;
                const int row = bm + lrow;
                if (row >= Mrows) continue;
                const float v = alpha * acc[i][j][r] + bv;
                if (v >= stau[lrow & 127]) {
                    const unsigned uu = __float_as_uint(v);
                    const unsigned key = (uu & 0x80000000u) ? ~uu : (uu | 0x80000000u);
                    const int s = atomicAdd(&lcnt[lrow & 127], 1);
                    if (s < SLOTS)
                        lcand[lrow & 127][s] = ((u64)(key ^ 0xffffffffu) << 32) | (unsigned)col;
                }
            }
        }
    }
    __syncthreads();
    if (tid < 128) {
        const int row = bm + tid;
        int c = lcnt[tid]; if (c > SLOTS) c = SLOTS;
        if (row < Mrows) {
            const size_t cell = (size_t)nt * Mrows + row;   // coalesced
            cnt2[cell] = c;
            u64* dst = pool + cell * SLOTS;
            for (int s = 0; s < c; ++s) dst[s] = lcand[tid][s];
        }
    }
}

// ---------------------------------------------------------------------------
// fp32 GEMM (query encoder / predictor; exact path)
// ---------------------------------------------------------------------------
#define TILE 64
#define KT   16
__global__ __launch_bounds__(256) void gemm_bias_act(
    const float* __restrict__ A, const float* __restrict__ B,
    const float* __restrict__ bias, float biasScale,
    const float* __restrict__ resid,
    float* __restrict__ C,
    int M, int N, int K, float alpha, int relu)
{
    __shared__ float As[KT][TILE + 4];
    __shared__ float Bs[KT][TILE + 4];
    const int bm = blockIdx.y * TILE;
    const int bn = blockIdx.x * TILE;
    const int tid = threadIdx.x;
    const int tx = tid & 15;
    const int ty = tid >> 4;
    const int lm = tid >> 2;
    const int lk = (tid & 3) * 4;

    float acc[4][4];
#pragma unroll
    for (int i = 0; i < 4; ++i)
#pragma unroll
        for (int j = 0; j < 4; ++j) acc[i][j] = 0.f;

    for (int k0 = 0; k0 < K; k0 += KT) {
        {
            const int gm = bm + lm;
            float4 v = make_float4(0.f, 0.f, 0.f, 0.f);
            if (gm < M) v = *reinterpret_cast<const float4*>(A + (size_t)gm * K + k0 + lk);
            As[lk + 0][lm] = v.x; As[lk + 1][lm] = v.y;
            As[lk + 2][lm] = v.z; As[lk + 3][lm] = v.w;
            const int gn = bn + lm;
            float4 u = make_float4(0.f, 0.f, 0.f, 0.f);
            if (gn < N) u = *reinterpret_cast<const float4*>(B + (size_t)gn * K + k0 + lk);
            Bs[lk + 0][lm] = u.x; Bs[lk + 1][lm] = u.y;
            Bs[lk + 2][lm] = u.z; Bs[lk + 3][lm] = u.w;
        }
        __syncthreads();
#pragma unroll
        for (int kk = 0; kk < KT; ++kk) {
            float aa[4], bb[4];
#pragma unroll
            for (int i = 0; i < 4; ++i) aa[i] = As[kk][ty * 4 + i];
#pragma unroll
            for (int j = 0; j < 4; ++j) bb[j] = Bs[kk][tx * 4 + j];
#pragma unroll
            for (int i = 0; i < 4; ++i)
#pragma unroll
                for (int j = 0; j < 4; ++j) acc[i][j] += aa[i] * bb[j];
        }
        __syncthreads();
    }
#pragma unroll
    for (int i = 0; i < 4; ++i) {
        const int gm = bm + ty * 4 + i;
        if (gm >= M) continue;
#pragma unroll
        for (int j = 0; j < 4; ++j) {
            const int gn = bn + tx * 4 + j;
            if (gn >= N) continue;
            float v = alpha * acc[i][j];
            if (bias)  v += biasScale * bias[gn];
            if (resid) v += resid[(size_t)gm * N + gn];
            if (relu)  v = fmaxf(v, 0.f);
            C[(size_t)gm * N + gn] = v;
        }
    }
}

// ---------------------------------------------------------------------------
// LayerNorm variants + small helpers
// ---------------------------------------------------------------------------
__global__ void ln_kernel(const float* __restrict__ X, const float* __restrict__ g,
                          const float* __restrict__ b, float* __restrict__ Y, int M)
{
    const int row = blockIdx.x * 4 + (threadIdx.x >> 6);
    const int lane = threadIdx.x & 63;
    if (row >= M) return;
    const float* x = X + (size_t)row * D_MAIN;
    float v[4]; float s = 0.f;
#pragma unroll
    for (int i = 0; i < 4; ++i) { v[i] = x[lane + 64 * i]; s += v[i]; }
#pragma unroll
    for (int o = 32; o > 0; o >>= 1) s += __shfl_xor(s, o);
    const float mu = s * (1.f / D_MAIN);
    float vs = 0.f;
#pragma unroll
    for (int i = 0; i < 4; ++i) { const float d = v[i] - mu; vs += d * d; }
#pragma unroll
    for (int o = 32; o > 0; o >>= 1) vs += __shfl_xor(vs, o);
    const float inv = rsqrtf(vs * (1.f / D_MAIN) + 1e-5f);
    float* y = Y + (size_t)row * D_MAIN;
#pragma unroll
    for (int i = 0; i < 4; ++i) {
        const int d = lane + 64 * i;
        y[d] = (v[i] - mu) * inv * g[d] + b[d];
    }
}

__global__ void ln_h2h_kernel(const _Float16* __restrict__ X, const float* __restrict__ g,
                              const float* __restrict__ b, _Float16* __restrict__ Y, int M)
{
    const int row = blockIdx.x * 4 + (threadIdx.x >> 6);
    const int lane = threadIdx.x & 63;
    if (row >= M) return;
    const _Float16* x = X + (size_t)row * D_MAIN;
    float v[4]; float s = 0.f;
#pragma unroll
    for (int i = 0; i < 4; ++i) { v[i] = (float)x[lane + 64 * i]; s += v[i]; }
#pragma unroll
    for (int o = 32; o > 0; o >>= 1) s += __shfl_xor(s, o);
    const float mu = s * (1.f / D_MAIN);
    float vs = 0.f;
#pragma unroll
    for (int i = 0; i < 4; ++i) { const float d = v[i] - mu; vs += d * d; }
#pragma unroll
    for (int o = 32; o > 0; o >>= 1) vs += __shfl_xor(vs, o);
    const float inv = rsqrtf(vs * (1.f / D_MAIN) + 1e-5f);
    _Float16* y = Y + (size_t)row * D_MAIN;
#pragma unroll
    for (int i = 0; i < 4; ++i) {
        const int d = lane + 64 * i;
        y[d] = (_Float16)((v[i] - mu) * inv * g[d] + b[d]);
    }
}

// rowsq + sampled-row gather fused
__global__ void rowsq_sample(const float* __restrict__ X, float* __restrict__ sq,
                             const bf* __restrict__ ckh,
                             bf* __restrict__ ckh_s, float* __restrict__ sqc_s, int M)
{
    const int row = blockIdx.x * 4 + (threadIdx.x >> 6);
    const int lane = threadIdx.x & 63;
    if (row >= M) return;
    const float* x = X + (size_t)row * D_MAIN;
    float s = 0.f;
#pragma unroll
    for (int i = 0; i < 4; ++i) { const float v = x[lane + 64 * i]; s += v * v; }
#pragma unroll
    for (int o = 32; o > 0; o >>= 1) s += __shfl_xor(s, o);
    if (lane == 0) sq[row] = s;
    if ((row & 15) == 0) {
        const int r = row >> 4;
        if (r < NS) {
            const bf* srcp = ckh + (size_t)row * D_MAIN;
            bf* dstp = ckh_s + (size_t)r * D_MAIN;
            *(short4*)(dstp + lane * 4) = *(const short4*)(srcp + lane * 4);
            if (lane == 0) sqc_s[r] = s;
        }
    }
}

__global__ void head_kernel(const float* __restrict__ X, const float* __restrict__ g,
                            const float* __restrict__ b, const float* __restrict__ W,
                            const float* __restrict__ bh, float* __restrict__ out, int M)
{
    const int row = blockIdx.x * 4 + (threadIdx.x >> 6);
    const int lane = threadIdx.x & 63;
    if (row >= M) return;
    const float* x = X + (size_t)row * D_MAIN;
    float v[4]; float s = 0.f;
#pragma unroll
    for (int i = 0; i < 4; ++i) { v[i] = x[lane + 64 * i]; s += v[i]; }
#pragma unroll
    for (int o = 32; o > 0; o >>= 1) s += __shfl_xor(s, o);
    const float mu = s * (1.f / D_MAIN);
    float vs = 0.f;
#pragma unroll
    for (int i = 0; i < 4; ++i) { const float d = v[i] - mu; vs += d * d; }
#pragma unroll
    for (int o = 32; o > 0; o >>= 1) vs += __shfl_xor(vs, o);
    const float inv = rsqrtf(vs * (1.f / D_MAIN) + 1e-5f);
    float acc = 0.f;
#pragma unroll
    for (int i = 0; i < 4; ++i) {
        const int d = lane + 64 * i;
        float o_ = (v[i] - mu) * inv * g[d] + b[d];
        o_ = fmaxf(o_, 0.f);
        acc += o_ * W[d];
    }
#pragma unroll
    for (int o = 32; o > 0; o >>= 1) acc += __shfl_xor(acc, o);
    if (lane == 0) out[row] = acc + bh[0];
}

__global__ void f2b_kernel(const float* __restrict__ in, bf* __restrict__ out, int n)
{
    const int i = blockIdx.x * 256 + threadIdx.x;
    if (i < n) out[i] = __float2bfloat16(in[i]);
}

// One-shot conversion of all weights/inputs (7 arrays, one launch).
__global__ void conv_all(
    const float* __restrict__ W_in, const float* __restrict__ W0a,
    const float* __restrict__ W0b, const float* __restrict__ W_k,
    const float* __restrict__ Xtr, const float* __restrict__ W_t1,
    const float* __restrict__ W_t2,
    _Float16* __restrict__ Win16, _Float16* __restrict__ W0a16,
    _Float16* __restrict__ W0b16, _Float16* __restrict__ Wk16,
    _Float16* __restrict__ Xtr16, bf* __restrict__ Wt1b, bf* __restrict__ Wt2b)
{
    const long n1 = D_MAIN * D_IN;
    const long n2 = D_BLOCK * D_MAIN;
    const long n3 = D_MAIN * D_BLOCK;
    const long n4 = D_MAIN * D_MAIN;
    const long n5 = (long)NTRAIN * D_IN;
    const long n6 = D_BLOCK * D_MAIN;
    const long total = n1 + n2 + n3 + n4 + n5 + n6 + (long)D_MAIN * D_BLOCK;
    for (long i = (long)blockIdx.x * 256 + threadIdx.x; i < total;
         i += (long)gridDim.x * 256) {
        long r = i;
        if (r < n1) { Win16[r] = (_Float16)W_in[r]; continue; } r -= n1;
        if (r < n2) { W0a16[r] = (_Float16)W0a[r]; continue; } r -= n2;
        if (r < n3) { W0b16[r] = (_Float16)W0b[r]; continue; } r -= n3;
        if (r < n4) { Wk16[r] = (_Float16)W_k[r]; continue; } r -= n4;
        if (r < n5) { Xtr16[r] = (_Float16)Xtr[r]; continue; } r -= n5;
        if (r < n6) { Wt1b[r] = __float2bfloat16(W_t1[r]); continue; } r -= n6;
        Wt2b[r] = __float2bfloat16(W_t2[r]);
    }
}

// tau[q] = exact TH_RANK-th largest sample score via 4-level radix select.
__global__ __launch_bounds__(256) void thresh_kernel(
    const float* __restrict__ ss, float* __restrict__ tau)
{
    const int q = blockIdx.x, tid = threadIdx.x;
    __shared__ union {
        unsigned h12[2][4096];
        struct { unsigned h8[4][256]; unsigned A[2048]; unsigned B[2048]; } r;
    } u;
    __shared__ unsigned cs[256];
    __shared__ int sh_bin, sh_need, cc;

    for (int i = tid; i < 8192; i += 256) ((unsigned*)u.h12)[i] = 0;
    __syncthreads();
    const int rep2 = (tid >> 7) & 1;
    for (int i = tid; i < NS; i += 256) {
        const unsigned uu = __float_as_uint(ss[(size_t)q * NS + i]);
        const unsigned key = (uu & 0x80000000u) ? ~uu : (uu | 0x80000000u);
        atomicAdd(&u.h12[rep2][key >> 20], 1u);
    }
    __syncthreads();
    unsigned s = 0;
    for (int b = tid * 16; b < tid * 16 + 16; ++b) s += u.h12[0][b] + u.h12[1][b];
    cs[tid] = s;
    __syncthreads();
    if (tid == 0) {
        unsigned cum = 0; int g = 255;
        for (; g > 0; --g) {
            if (cum + cs[g] >= (unsigned)TH_RANK) break;
            cum += cs[g];
        }
        int b = g * 16;
        for (int bb = g * 16 + 15; bb >= g * 16; --bb) {
            const unsigned c = u.h12[0][bb] + u.h12[1][bb];
            if (cum + c >= (unsigned)TH_RANK) { b = bb; break; }
            cum += c;
        }
        sh_bin = b; sh_need = TH_RANK - (int)cum; cc = 0;
    }
    __syncthreads();
    const unsigned bin12 = (unsigned)sh_bin;
    for (int i = tid; i < NS; i += 256) {
        const unsigned uu = __float_as_uint(ss[(size_t)q * NS + i]);
        const unsigned key = (uu & 0x80000000u) ? ~uu : (uu | 0x80000000u);
        if ((key >> 20) == bin12) {
            const int p = atomicAdd(&cc, 1);
            if (p < 2048) u.r.A[p] = key;
        }
    }
    __syncthreads();
    int E = cc < 2048 ? cc : 2048;
    unsigned* src = u.r.A;
    unsigned* dst = u.r.B;
    const int rep4 = tid >> 6;
    for (int lvl = 0; lvl < 3; ++lvl) {
        const int sh = (lvl == 0) ? 12 : (lvl == 1) ? 4 : 0;
        const unsigned msk = (lvl == 2) ? 15u : 255u;
        const int nb = (lvl == 2) ? 16 : 256;
        for (int i = tid; i < 1024; i += 256) ((unsigned*)u.r.h8)[i] = 0;
        if (tid == 0) cc = 0;
        __syncthreads();
        for (int e = tid; e < E; e += 256) atomicAdd(&u.r.h8[rep4][(src[e] >> sh) & msk], 1u);
        __syncthreads();
        if (tid == 0) {
            const int need = sh_need;
            unsigned cum = 0; int b = nb - 1;
            for (; b > 0; --b) {
                const unsigned c = u.r.h8[0][b] + u.r.h8[1][b] + u.r.h8[2][b] + u.r.h8[3][b];
                if (cum + c >= (unsigned)need) break;
                cum += c;
            }
            sh_bin = b; sh_need = need - (int)cum;
        }
        __syncthreads();
        const unsigned b = (unsigned)sh_bin;
        for (int e = tid; e < E; e += 256) {
            if (((src[e] >> sh) & msk) == b) {
                const int p = atomicAdd(&cc, 1);
                if (p < 2048) dst[p] = src[e];
            }
        }
        __syncthreads();
        E = cc < 2048 ? cc : 2048;
        unsigned* t = src; src = dst; dst = t;
        __syncthreads();
    }
    if (tid == 0) {
        const unsigned key = src[0];
        const unsigned uu = (key & 0x80000000u) ? (key & 0x7fffffffu) : ~key;
        tau[q] = __uint_as_float(uu);
    }
}

// per chunk-local query: gather candidates from transposed (cnt2, pool) cells,
// then top-128 by (score desc, col asc) via bitonic over dynamic pow-2 size.
__global__ __launch_bounds__(256) void select_kernel(
    const u64* __restrict__ pool, const int* __restrict__ cnt2,
    int* __restrict__ idx128, int nN, int q0, int Mrows)
{
    const int q = blockIdx.x, tid = threadIdx.x;
    __shared__ u64 k[CAND_CAP];
    __shared__ int lc;
    if (tid == 0) lc = 0;
    __syncthreads();
    for (int t = tid; t < nN; t += 256) {
        const size_t cell = (size_t)t * Mrows + q;
        const int c = cnt2[cell];
        const u64* src = pool + cell * SLOTS;
        for (int s = 0; s < c; ++s) {
            const int p = atomicAdd(&lc, 1);
            if (p < CAND_CAP) k[p] = src[s];
        }
    }
    __syncthreads();
    int E = lc; if (E > CAND_CAP) E = CAND_CAP;
    int P = K_PRE; while (P < E) P <<= 1;
    for (int i = tid; i < P; i += 256)
        if (i >= E) k[i] = ~0ull;
    __syncthreads();
    for (int kk = 2; kk <= P; kk <<= 1) {
        for (int j = kk >> 1; j > 0; j >>= 1) {
            for (int i = tid; i < P; i += 256) {
                const int ixj = i ^ j;
                if (ixj > i) {
                    const bool up = ((i & kk) == 0);
                    const u64 a = k[i], b2 = k[ixj];
                    if ((a > b2) == up) { k[i] = b2; k[ixj] = a; }
                }
            }
            __syncthreads();
        }
    }
    if (tid < K_PRE) {
        const u64 e = (tid < E) ? k[tid] : k[0];
        idx128[(size_t)(q0 + q) * K_PRE + tid] = (int)(e & 0xffffffffu);
    }
}

// ---------------------------------------------------------------------------
// Exact re-rank + fused diff write: fp32 d2 over 128 candidates, top-96 with
// (d2, idx) tie rule, sims out; then writes bf16 diff rows for the 96 winners.
// ---------------------------------------------------------------------------
__global__ __launch_bounds__(256) void rerank_kernel(
    const float* __restrict__ k_q, const float* __restrict__ ck,
    const int* __restrict__ idx128, int* __restrict__ idx96,
    float* __restrict__ sims96, bf* __restrict__ diff)
{
    const int q = blockIdx.x;
    const int tid = threadIdx.x;
    const int w = tid >> 6, lam = tid & 63;
    __shared__ float kq[D_MAIN];
    __shared__ u64 keys[K_PRE];
    kq[tid] = k_q[(size_t)q * D_MAIN + tid];
    __syncthreads();

    for (int c = w * 32; c < w * 32 + 32; ++c) {
        const int j = idx128[(size_t)q * K_PRE + c];
        const float4 cv = *(const float4*)(ck + (size_t)j * D_MAIN + lam * 4);
        const float d0 = kq[lam * 4 + 0] - cv.x;
        const float d1 = kq[lam * 4 + 1] - cv.y;
        const float d2_ = kq[lam * 4 + 2] - cv.z;
        const float d3 = kq[lam * 4 + 3] - cv.w;
        float s = d0 * d0 + d1 * d1 + d2_ * d2_ + d3 * d3;
#pragma unroll
        for (int o = 32; o > 0; o >>= 1) s += __shfl_xor(s, o);
        if (lam == 0)
            keys[c] = ((u64)__float_as_uint(s) << 32) | (unsigned)j;
    }
    __syncthreads();

    for (int k = 2; k <= K_PRE; k <<= 1) {
        for (int j = k >> 1; j > 0; j >>= 1) {
            if (tid < K_PRE) {
                const int ixj = tid ^ j;
                if (ixj > tid) {
                    const bool up = ((tid & k) == 0);
                    const u64 a = keys[tid], b2 = keys[ixj];
                    if ((a > b2) == up) { keys[tid] = b2; keys[ixj] = a; }
                }
            }
            __syncthreads();
        }
    }
    u64 k2 = ~0ull;
    if (tid < CTX) k2 = (keys[tid] << 32) | (keys[tid] >> 32);
    __syncthreads();
    if (tid < K_PRE) keys[tid] = k2;
    __syncthreads();
    for (int k = 2; k <= K_PRE; k <<= 1) {
        for (int j = k >> 1; j > 0; j >>= 1) {
            if (tid < K_PRE) {
                const int ixj = tid ^ j;
                if (ixj > tid) {
                    const bool up = ((tid & k) == 0);
                    const u64 a = keys[tid], b2 = keys[ixj];
                    if ((a > b2) == up) { keys[tid] = b2; keys[ixj] = a; }
                }
            }
            __syncthreads();
        }
    }
    if (tid < CTX) {
        idx96[(size_t)q * CTX + tid] = (int)(keys[tid] >> 32);
        sims96[(size_t)q * CTX + tid] = -__uint_as_float((unsigned)(keys[tid] & 0xffffffffu));
    }
    __syncthreads();
    for (int c = w; c < CTX; c += 4) {
        const int j = (int)(keys[c] >> 32);
        const float4 cv = *(const float4*)(ck + (size_t)j * D_MAIN + lam * 4);
        bf tmp[4];
        tmp[0] = __float2bfloat16(kq[lam * 4 + 0] - cv.x);
        tmp[1] = __float2bfloat16(kq[lam * 4 + 1] - cv.y);
        tmp[2] = __float2bfloat16(kq[lam * 4 + 2] - cv.z);
        tmp[3] = __float2bfloat16(kq[lam * 4 + 3] - cv.w);
        bf* drow = diff + ((size_t)q * CTX + c) * D_MAIN + lam * 4;
        *(short4*)drow = *(short4*)tmp;
    }
}

__global__ void combine_kernel(const float* __restrict__ sscA, const int* __restrict__ idxA,
                               const float* __restrict__ ytr, const float* __restrict__ w_lab,
                               const float* __restrict__ b_lab, const bf* __restrict__ vv,
                               float* __restrict__ x_q, int q0)
{
    const int q = q0 + blockIdx.x;
    __shared__ float pr[CTX];
    __shared__ float sh_ybar;
    const int tid = threadIdx.x;
    if (tid == 0) {
        float mx = -1e30f;
        for (int c = 0; c < CTX; ++c) mx = fmaxf(mx, sscA[(size_t)q * CTX + c]);
        float sum = 0.f;
        for (int c = 0; c < CTX; ++c) {
            const float e = __expf(sscA[(size_t)q * CTX + c] - mx);
            pr[c] = e; sum += e;
        }
        const float inv = 1.f / sum;
        float yb = 0.f;
        for (int c = 0; c < CTX; ++c) {
            pr[c] *= inv;
            yb += pr[c] * ytr[idxA[(size_t)q * CTX + c]];
        }
        sh_ybar = yb;
    }
    __syncthreads();
    const int d = tid;
    float acc = 0.f;
    const bf* vq = vv + (size_t)blockIdx.x * CTX * D_MAIN;
    for (int c = 0; c < CTX; ++c) acc += pr[c] * __bfloat162float(vq[(size_t)c * D_MAIN + d]);
    x_q[(size_t)q * D_MAIN + d] += acc + sh_ybar * w_lab[d] + b_lab[d];
}

// ---------------------------------------------------------------------------
extern "C" void kernel_launch(void* const* d_in, const int* in_sizes, int n_in,
                              void* d_out, int out_size, void* d_ws, size_t ws_size,
                              hipStream_t stream)
{
    const float* X      = (const float*)d_in[0];
    const float* Xtr    = (const float*)d_in[1];
    const float* ytr    = (const float*)d_in[2];
    const float* W_in   = (const float*)d_in[3];
    const float* b_in   = (const float*)d_in[4];
    const float* W0a    = (const float*)d_in[5];
    const float* b0a    = (const float*)d_in[6];
    const float* W0b    = (const float*)d_in[7];
    const float* b0b    = (const float*)d_in[8];
    const float* g_mix  = (const float*)d_in[9];
    const float* be_mix = (const float*)d_in[10];
    const float* W_k    = (const float*)d_in[11];
    const float* b_k    = (const float*)d_in[12];
    const float* w_lab  = (const float*)d_in[13];
    const float* b_lab  = (const float*)d_in[14];
    const float* W_t1   = (const float*)d_in[15];
    const float* b_t1   = (const float*)d_in[16];
    const float* W_t2   = (const float*)d_in[17];
    const float* g_p    = (const float*)d_in[18];
    const float* be_p   = (const float*)d_in[19];
    const float* W1a    = (const float*)d_in[20];
    const float* b1a    = (const float*)d_in[21];
    const float* W1b    = (const float*)d_in[22];
    const float* b1b    = (const float*)d_in[23];
    const float* g_h    = (const float*)d_in[24];
    const float* be_h   = (const float*)d_in[25];
    const float* W_h    = (const float*)d_in[26];
    const float* b_h    = (const float*)d_in[27];
    float* out = (float*)d_out;

    char* ws = (char*)d_ws;
    size_t off = 0;
    auto alloc = [&](size_t bytes) -> void* {
        void* p = ws + off;
        off += (bytes + 255) & ~(size_t)255;
        return p;
    };
    float*     ck    = (float*)alloc((size_t)NTRAIN * D_MAIN * 4);
    bf*        ckh   = (bf*)   alloc((size_t)NTRAIN * D_MAIN * 2);
    float*     sqc   = (float*)alloc((size_t)NTRAIN * 4);
    _Float16*  Xtr16 = (_Float16*)alloc((size_t)NTRAIN * D_IN * 2);
    _Float16*  Win16 = (_Float16*)alloc((size_t)D_MAIN * D_IN * 2);
    _Float16*  W0a16 = (_Float16*)alloc((size_t)D_BLOCK * D_MAIN * 2);
    _Float16*  W0b16 = (_Float16*)alloc((size_t)D_MAIN * D_BLOCK * 2);
    _Float16*  Wk16  = (_Float16*)alloc((size_t)D_MAIN * D_MAIN * 2);
    bf*        Wt1b  = (bf*)   alloc((size_t)D_BLOCK * D_MAIN * 2);
    bf*        Wt2b  = (bf*)   alloc((size_t)D_MAIN * D_BLOCK * 2);
    float*     x_q   = (float*)alloc((size_t)NQ * D_MAIN * 4);
    float*     h_q   = (float*)alloc((size_t)NQ * D_MAIN * 4);
    float*     t_q   = (float*)alloc((size_t)NQ * D_BLOCK * 4);
    float*     ln_q  = (float*)alloc((size_t)NQ * D_MAIN * 4);
    float*     k_q   = (float*)alloc((size_t)NQ * D_MAIN * 4);
    bf*        k_qb  = (bf*)   alloc((size_t)NQ * D_MAIN * 2);
    int*       idx128 = (int*) alloc((size_t)NQ * K_PRE * 4);
    int*       idxA  = (int*)  alloc((size_t)NQ * CTX * 4);
    float*     sscA  = (float*)alloc((size_t)NQ * CTX * 4);
    bf*        ckh_s = (bf*)   alloc((size_t)NS * D_MAIN * 2);
    float*     sqc_s = (float*)alloc((size_t)NS * 4);
    float*     tauA  = (float*)alloc((size_t)NQ * 4);

    const size_t bigOff = off;
    const size_t bigBytes = (ws_size > bigOff) ? (ws_size - bigOff) : 0;
    char* big = ws + bigOff;

    // one-shot conversions
    conv_all<<<2048, 256, 0, stream>>>(W_in, W0a, W0b, W_k, Xtr, W_t1, W_t2,
        Win16, W0a16, W0b16, Wk16, Xtr16, Wt1b, Wt2b);

    // ---------------- encode queries (fp32 exact) ----------------
    {
        dim3 g1((D_MAIN + TILE - 1) / TILE, (NQ + TILE - 1) / TILE);
        gemm_bias_act<<<g1, 256, 0, stream>>>(X, W_in, b_in, 1.f, nullptr, h_q, NQ, D_MAIN, D_IN, 1.f, 0);
        dim3 g2((D_BLOCK + TILE - 1) / TILE, (NQ + TILE - 1) / TILE);
        gemm_bias_act<<<g2, 256, 0, stream>>>(h_q, W0a, b0a, 1.f, nullptr, t_q, NQ, D_BLOCK, D_MAIN, 1.f, 1);
        gemm_bias_act<<<g1, 256, 0, stream>>>(t_q, W0b, b0b, 1.f, h_q, x_q, NQ, D_MAIN, D_BLOCK, 1.f, 0);
        ln_kernel<<<(NQ + 3) / 4, 256, 0, stream>>>(x_q, g_mix, be_mix, ln_q, NQ);
        gemm_bias_act<<<g1, 256, 0, stream>>>(ln_q, W_k, b_k, 1.f, nullptr, k_q, NQ, D_MAIN, D_MAIN, 1.f, 0);
        f2b_kernel<<<(NQ * D_MAIN + 255) / 256, 256, 0, stream>>>(k_q, k_qb, NQ * D_MAIN);
    }

    // ---------------- encode train (fp16 MFMA, in-place x; 1.5KB/row) -------
    {
        long Rmax = (long)(bigBytes / 1536);
        int R = (int)(Rmax < 100096 ? Rmax : 100096);
        R &= ~127;
        if (R < 128) R = 128;
        _Float16* h16  = (_Float16*)big;                       // R*512 B (x in-place)
        _Float16* t16  = (_Float16*)(big + (size_t)R * 512);   // R*1024 B
        _Float16* ln16 = t16;                                  // alias (t dead after W0b)
        for (int r0 = 0; r0 < NTRAIN; r0 += R) {
            const int Rc = (NTRAIN - r0 < R) ? (NTRAIN - r0) : R;
            dim3 gA(2, (Rc + 127) / 128);
            dim3 gB(4, (Rc + 127) / 128);
            gemm_fp16<<<gA, 256, 0, stream>>>(Xtr16 + (size_t)r0 * D_IN, Win16,
                Rc, D_MAIN, D_IN, b_in, nullptr, nullptr, h16, nullptr, 0);
            gemm_fp16<<<gB, 256, 0, stream>>>(h16, W0a16, Rc, D_BLOCK, D_MAIN,
                b0a, nullptr, nullptr, t16, nullptr, 1);
            gemm_fp16<<<gA, 256, 0, stream>>>(t16, W0b16, Rc, D_MAIN, D_BLOCK,
                b0b, h16, nullptr, h16, nullptr, 0);
            ln_h2h_kernel<<<(Rc + 3) / 4, 256, 0, stream>>>(h16, g_mix, be_mix, ln16, Rc);
            gemm_fp16<<<gA, 256, 0, stream>>>(ln16, Wk16, Rc, D_MAIN, D_MAIN,
                b_k, nullptr, ck + (size_t)r0 * D_MAIN, nullptr,
                ckh + (size_t)r0 * D_MAIN, 0);
        }
    }
    rowsq_sample<<<(NTRAIN + 3) / 4, 256, 0, stream>>>(ck, sqc, ckh, ckh_s, sqc_s, NTRAIN);

    // ---------------- phase A: sampled-threshold selection (atomic-free) -----
    {
        float* scores_s = (float*)big;      // 25.6 MB; dead after thresh
        dim3 gss((NS + 127) / 128, (NQ + 127) / 128);
        gemm_bf16<<<gss, 256, 0, stream>>>(k_qb, ckh_s, NQ, NS, D_MAIN,
            2.f, sqc_s, -1.f, scores_s, nullptr, 0);
        thresh_kernel<<<NQ, 256, 0, stream>>>(scores_s, tauA);

        const int nN = (NTRAIN + 127) / 128;          // 782 N-tiles
        const size_t perRow = (size_t)nN * SLOTS * 8 + (size_t)nN * 4 + 256;
        int Qc = 128, mshift = 0;
        while (Qc < NQ && (size_t)(Qc * 2) * perRow <= bigBytes) { Qc <<= 1; ++mshift; }
        const int nGroups = (nN + 7) / 8;
        for (int q0 = 0; q0 < NQ; q0 += Qc) {
            u64* pool = (u64*)big;                    // reuses scores_s space
            int* cnt2 = (int*)(big + (size_t)Qc * nN * SLOTS * 8);
            gemm_bf16_filter<<<nGroups * 8 * (Qc / 128), 256, 0, stream>>>(
                k_qb + (size_t)q0 * D_MAIN, ckh, Qc, NTRAIN, D_MAIN,
                2.f, sqc, -1.f, tauA + q0, pool, cnt2, nN, mshift);
            select_kernel<<<Qc, 256, 0, stream>>>(pool, cnt2, idx128, nN, q0, Qc);
        }
    }

    // ---------------- phase B: exact re-rank + fused diff write --------------
    const size_t diffBytes = ((size_t)NQ * CTX * D_MAIN * 2 + 255) & ~(size_t)255;
    bf* diffAll = (bf*)big;
    rerank_kernel<<<NQ, 256, 0, stream>>>(k_q, ck, idx128, idxA, sscA, diffAll);

    // ---------------- phase C: values MLP + combine (chunked) ----------------
    {
        char* cbase = big + diffBytes;
        const size_t cBytes = (bigBytes > diffBytes) ? (bigBytes - diffBytes) : 0;
        const size_t perQ = (size_t)CTX * (D_BLOCK * 2 + D_MAIN * 2); // tt + vvh
        long Qmax = (long)(cBytes / perQ);
        int Q = (int)(Qmax < NQ ? Qmax : NQ);
        if (Q < 1) Q = 1;
        for (int q0 = 0; q0 < NQ; q0 += Q) {
            const int Qc = (NQ - q0 < Q) ? (NQ - q0) : Q;
            bf* tt  = (bf*)cbase;
            bf* vvh = (bf*)(cbase + (size_t)Qc * CTX * D_BLOCK * 2);
            dim3 g1((D_BLOCK + 127) / 128, (Qc * CTX + 127) / 128);
            gemm_bf16<<<g1, 256, 0, stream>>>(diffAll + (size_t)q0 * CTX * D_MAIN, Wt1b,
                Qc * CTX, D_BLOCK, D_MAIN, 1.f, b_t1, 1.f, nullptr, tt, 1);
            dim3 g2((D_MAIN + 127) / 128, (Qc * CTX + 127) / 128);
            gemm_bf16<<<g2, 256, 0, stream>>>(tt, Wt2b, Qc * CTX, D_MAIN, D_BLOCK,
                1.f, nullptr, 0.f, nullptr, vvh, 0);
            combine_kernel<<<Qc, 256, 0, stream>>>(sscA, idxA, ytr, w_lab, b_lab, vvh, x_q, q0);
        }
    }

    // ---------------- predictor + head (fp32 exact) ----------------
    {
        dim3 g1((D_MAIN + TILE - 1) / TILE, (NQ + TILE - 1) / TILE);
        dim3 g2((D_BLOCK + TILE - 1) / TILE, (NQ + TILE - 1) / TILE);
        ln_kernel<<<(NQ + 3) / 4, 256, 0, stream>>>(x_q, g_p, be_p, ln_q, NQ);
        gemm_bias_act<<<g2, 256, 0, stream>>>(ln_q, W1a, b1a, 1.f, nullptr, t_q, NQ, D_BLOCK, D_MAIN, 1.f, 1);
        gemm_bias_act<<<g1, 256, 0, stream>>>(t_q, W1b, b1b, 1.f, x_q, x_q, NQ, D_MAIN, D_BLOCK, 1.f, 0);
        head_kernel<<<(NQ + 3) / 4, 256, 0, stream>>>(x_q, g_h, be_h, W_h, b_h, out, NQ);
    }
}

// Round 17
// 1171.933 us; speedup vs baseline: 1.1497x; 1.0044x over previous
//
#include <hip/hip_runtime.h>
#include <hip/hip_bf16.h>
#include <cstdint>
#include <cstddef>

#define D_IN    32
#define D_MAIN  256
#define D_BLOCK 512
#define CTX     96
#define K_PRE   128
#define NQ      1024
#define NTRAIN  100000
#define NS      6250      // sampled candidates (stride 16)
#define TH_RANK 48        // sample rank for threshold -> ~768 expected candidates
#define CAND_CAP 2048
#define SLOTS   12        // per (row, 128-col tile) candidate slots

typedef __attribute__((ext_vector_type(8))) short bf16x8;
typedef __attribute__((ext_vector_type(8))) _Float16 f16x8;
typedef __attribute__((ext_vector_type(4))) float f32x4;
typedef __hip_bfloat16 bf;
typedef unsigned long long u64;

#define GLL(gp, lp) __builtin_amdgcn_global_load_lds( \
    (const __attribute__((address_space(1))) void*)(gp), \
    (__attribute__((address_space(3))) void*)(lp), 16, 0, 0)

// ---------------------------------------------------------------------------
// Plain bf16 MFMA GEMM: C = act(alpha*(A@B^T) + biasScale*bias[n])
// 128x128 tile, BK=32, 4 waves, 16x16x32 MFMA, XOR-swizzled LDS staging.
// ---------------------------------------------------------------------------
__global__ __launch_bounds__(256) void gemm_bf16(
    const bf* __restrict__ A, const bf* __restrict__ B,
    int M, int N, int K, float alpha,
    const float* __restrict__ bias, float biasScale,
    float* __restrict__ Cf, bf* __restrict__ Ch, int relu)
{
    __shared__ __align__(16) char smem[16384];
    const int tid = threadIdx.x;
    const int w   = tid >> 6;
    const int lam = tid & 63;
    const int bm  = blockIdx.y * 128;
    const int bn  = blockIdx.x * 128;
    const int wm  = w >> 1, wn = w & 1;

    f32x4 acc[4][4];
#pragma unroll
    for (int i = 0; i < 4; ++i)
#pragma unroll
        for (int j = 0; j < 4; ++j) acc[i][j] = (f32x4){0.f, 0.f, 0.f, 0.f};

    const int r0s  = w * 16 + (lam >> 2);
    const int slot = lam & 3;
    const int g0   = slot ^ ((r0s >> 1) & 3);
    const int g1   = slot ^ (((r0s + 64) >> 1) & 3);
    const size_t strideAB = (size_t)K * 2;
    long ga0 = bm + r0s;      if (ga0 >= M) ga0 = M - 1;
    long ga1 = bm + r0s + 64; if (ga1 >= M) ga1 = M - 1;
    long gb0 = bn + r0s;      if (gb0 >= N) gb0 = N - 1;
    long gb1 = bn + r0s + 64; if (gb1 >= N) gb1 = N - 1;
    const char* pa0 = (const char*)A + (size_t)ga0 * strideAB + 16 * g0;
    const char* pa1 = (const char*)A + (size_t)ga1 * strideAB + 16 * g1;
    const char* pb0 = (const char*)B + (size_t)gb0 * strideAB + 16 * g0;
    const char* pb1 = (const char*)B + (size_t)gb1 * strideAB + 16 * g1;

    const int sread = (lam >> 4) ^ ((lam >> 1) & 3);
    const int abase = wm * 4096 + (lam & 15) * 64 + sread * 16;
    const int bbase = 8192 + wn * 4096 + (lam & 15) * 64 + sread * 16;

    for (int k0 = 0; k0 < K; k0 += 32) {
        __syncthreads();
        const size_t kb = 2 * (size_t)k0;
        GLL(pa0 + kb, smem + w * 1024);
        GLL(pa1 + kb, smem + 4096 + w * 1024);
        GLL(pb0 + kb, smem + 8192 + w * 1024);
        GLL(pb1 + kb, smem + 12288 + w * 1024);
        asm volatile("s_waitcnt vmcnt(0)" ::: "memory");
        __syncthreads();

        bf16x8 aF[4], bF[4];
#pragma unroll
        for (int i = 0; i < 4; ++i) aF[i] = *(const bf16x8*)(smem + abase + 1024 * i);
#pragma unroll
        for (int j = 0; j < 4; ++j) bF[j] = *(const bf16x8*)(smem + bbase + 1024 * j);
#pragma unroll
        for (int i = 0; i < 4; ++i)
#pragma unroll
            for (int j = 0; j < 4; ++j)
                acc[i][j] = __builtin_amdgcn_mfma_f32_16x16x32_bf16(aF[i], bF[j], acc[i][j], 0, 0, 0);
    }

    const int col0 = bn + wn * 64 + (lam & 15);
    const int row0 = bm + wm * 64 + ((lam >> 4) << 2);
#pragma unroll
    for (int j = 0; j < 4; ++j) {
        const int col = col0 + 16 * j;
        if (col >= N) continue;
        const float bv = bias ? biasScale * bias[col] : 0.f;
#pragma unroll
        for (int i = 0; i < 4; ++i) {
#pragma unroll
            for (int r = 0; r < 4; ++r) {
                const int row = row0 + 16 * i + r;
                if (row >= M) continue;
                float v = alpha * acc[i][j][r] + bv;
                if (relu) v = fmaxf(v, 0.f);
                const size_t idx = (size_t)row * N + col;
                if (Cf) Cf[idx] = v;
                if (Ch) Ch[idx] = __float2bfloat16(v);
            }
        }
    }
}

// ---------------------------------------------------------------------------
// Plain fp16 MFMA GEMM: C = act(A@B^T + bias[n] (+ res16) (+ resF))
// Outputs: fp32 / fp16 / bf16 (any subset). res16/resF may alias outputs
// (same-index read-then-write within one thread).
// ---------------------------------------------------------------------------
__global__ __launch_bounds__(256) void gemm_fp16(
    const _Float16* __restrict__ A, const _Float16* __restrict__ B,
    int M, int N, int K,
    const float* __restrict__ bias, const _Float16* res16, const float* resF,
    float* Cf, _Float16* Ch, bf* __restrict__ Cb,
    int relu)
{
    __shared__ __align__(16) char smem[16384];
    const int tid = threadIdx.x;
    const int w   = tid >> 6;
    const int lam = tid & 63;
    const int bm  = blockIdx.y * 128;
    const int bn  = blockIdx.x * 128;
    const int wm  = w >> 1, wn = w & 1;

    f32x4 acc[4][4];
#pragma unroll
    for (int i = 0; i < 4; ++i)
#pragma unroll
        for (int j = 0; j < 4; ++j) acc[i][j] = (f32x4){0.f, 0.f, 0.f, 0.f};

    const int r0s  = w * 16 + (lam >> 2);
    const int slot = lam & 3;
    const int g0   = slot ^ ((r0s >> 1) & 3);
    const int g1   = slot ^ (((r0s + 64) >> 1) & 3);
    const size_t strideAB = (size_t)K * 2;
    long ga0 = bm + r0s;      if (ga0 >= M) ga0 = M - 1;
    long ga1 = bm + r0s + 64; if (ga1 >= M) ga1 = M - 1;
    long gb0 = bn + r0s;      if (gb0 >= N) gb0 = N - 1;
    long gb1 = bn + r0s + 64; if (gb1 >= N) gb1 = N - 1;
    const char* pa0 = (const char*)A + (size_t)ga0 * strideAB + 16 * g0;
    const char* pa1 = (const char*)A + (size_t)ga1 * strideAB + 16 * g1;
    const char* pb0 = (const char*)B + (size_t)gb0 * strideAB + 16 * g0;
    const char* pb1 = (const char*)B + (size_t)gb1 * strideAB + 16 * g1;

    const int sread = (lam >> 4) ^ ((lam >> 1) & 3);
    const int abase = wm * 4096 + (lam & 15) * 64 + sread * 16;
    const int bbase = 8192 + wn * 4096 + (lam & 15) * 64 + sread * 16;

    for (int k0 = 0; k0 < K; k0 += 32) {
        __syncthreads();
        const size_t kb = 2 * (size_t)k0;
        GLL(pa0 + kb, smem + w * 1024);
        GLL(pa1 + kb, smem + 4096 + w * 1024);
        GLL(pb0 + kb, smem + 8192 + w * 1024);
        GLL(pb1 + kb, smem + 12288 + w * 1024);
        asm volatile("s_waitcnt vmcnt(0)" ::: "memory");
        __syncthreads();

        f16x8 aF[4], bF[4];
#pragma unroll
        for (int i = 0; i < 4; ++i) aF[i] = *(const f16x8*)(smem + abase + 1024 * i);
#pragma unroll
        for (int j = 0; j < 4; ++j) bF[j] = *(const f16x8*)(smem + bbase + 1024 * j);
#pragma unroll
        for (int i = 0; i < 4; ++i)
#pragma unroll
            for (int j = 0; j < 4; ++j)
                acc[i][j] = __builtin_amdgcn_mfma_f32_16x16x32_f16(aF[i], bF[j], acc[i][j], 0, 0, 0);
    }

    const int col0 = bn + wn * 64 + (lam & 15);
    const int row0 = bm + wm * 64 + ((lam >> 4) << 2);
#pragma unroll
    for (int j = 0; j < 4; ++j) {
        const int col = col0 + 16 * j;
        if (col >= N) continue;
        const float bv = bias ? bias[col] : 0.f;
#pragma unroll
        for (int i = 0; i < 4; ++i) {
#pragma unroll
            for (int r = 0; r < 4; ++r) {
                const int row = row0 + 16 * i + r;
                if (row >= M) continue;
                float v = acc[i][j][r] + bv;
                const size_t idx = (size_t)row * N + col;
                if (res16) v += (float)res16[idx];
                if (resF)  v += resF[idx];
                if (relu) v = fmaxf(v, 0.f);
                if (Cf) Cf[idx] = v;
                if (Ch) Ch[idx] = (_Float16)v;
                if (Cb) Cb[idx] = __float2bfloat16(v);
            }
        }
    }
}

// ---------------------------------------------------------------------------
// Filter GEMM (BM=128) over a chunk of Mrows query rows.
// XCD-pinned 1D grid: b -> nl=b&7, mt=(b>>3)&(mtiles-1), nt=(b>>(3+mshift))*8+nl.
// ATOMIC-FREE epilogue, COALESCED cells (nt*Mrows + row).
// ---------------------------------------------------------------------------
__global__ __launch_bounds__(256) void gemm_bf16_filter(
    const bf* __restrict__ A, const bf* __restrict__ B,
    int Mrows, int N, int K, float alpha,
    const float* __restrict__ bias, float biasScale,
    const float* __restrict__ tau,
    u64* __restrict__ pool, int* __restrict__ cnt2, int nN, int mshift)
{
    __shared__ __align__(16) char smem[16384];
    __shared__ int lcnt[128];
    __shared__ float stau[128];
    __shared__ u64 lcand[128][SLOTS];
    const int bidx = blockIdx.x;
    const int nl = bidx & 7;
    const int mt = (bidx >> 3) & ((1 << mshift) - 1);
    const int nt = (bidx >> (3 + mshift)) * 8 + nl;
    if (nt >= nN) return;
    const int bm = mt * 128;
    const int bn = nt * 128;

    const int tid = threadIdx.x;
    const int w   = tid >> 6;
    const int lam = tid & 63;
    const int wm  = w >> 1, wn = w & 1;

    if (tid < 128) { lcnt[tid] = 0; stau[tid] = tau[bm + tid]; }

    f32x4 acc[4][4];
#pragma unroll
    for (int i = 0; i < 4; ++i)
#pragma unroll
        for (int j = 0; j < 4; ++j) acc[i][j] = (f32x4){0.f, 0.f, 0.f, 0.f};

    const int r0s  = w * 16 + (lam >> 2);
    const int slot = lam & 3;
    const int g0   = slot ^ ((r0s >> 1) & 3);
    const int g1   = slot ^ (((r0s + 64) >> 1) & 3);
    const size_t strideAB = (size_t)K * 2;
    long ga0 = bm + r0s;      if (ga0 >= Mrows) ga0 = Mrows - 1;
    long ga1 = bm + r0s + 64; if (ga1 >= Mrows) ga1 = Mrows - 1;
    long gb0 = bn + r0s;      if (gb0 >= N) gb0 = N - 1;
    long gb1 = bn + r0s + 64; if (gb1 >= N) gb1 = N - 1;
    const char* pa0 = (const char*)A + (size_t)ga0 * strideAB + 16 * g0;
    const char* pa1 = (const char*)A + (size_t)ga1 * strideAB + 16 * g1;
    const char* pb0 = (const char*)B + (size_t)gb0 * strideAB + 16 * g0;
    const char* pb1 = (const char*)B + (size_t)gb1 * strideAB + 16 * g1;

    const int sread = (lam >> 4) ^ ((lam >> 1) & 3);
    const int abase = wm * 4096 + (lam & 15) * 64 + sread * 16;
    const int bbase = 8192 + wn * 4096 + (lam & 15) * 64 + sread * 16;

    for (int k0 = 0; k0 < K; k0 += 32) {
        __syncthreads();
        const size_t kb = 2 * (size_t)k0;
        GLL(pa0 + kb, smem + w * 1024);
        GLL(pa1 + kb, smem + 4096 + w * 1024);
        GLL(pb0 + kb, smem + 8192 + w * 1024);
        GLL(pb1 + kb, smem + 12288 + w * 1024);
        asm volatile("s_waitcnt vmcnt(0)" ::: "memory");
        __syncthreads();

        bf16x8 aF[4], bF[4];
#pragma unroll
        for (int i = 0; i < 4; ++i) aF[i] = *(const bf16x8*)(smem + abase + 1024 * i);
#pragma unroll
        for (int j = 0; j < 4; ++j) bF[j] = *(const bf16x8*)(smem + bbase + 1024 * j);
#pragma unroll
        for (int i = 0; i < 4; ++i)
#pragma unroll
            for (int j = 0; j < 4; ++j)
                acc[i][j] = __builtin_amdgcn_mfma_f32_16x16x32_bf16(aF[i], bF[j], acc[i][j], 0, 0, 0);
    }

    const int col0 = bn + wn * 64 + (lam & 15);
    const int lrow0 = wm * 64 + ((lam >> 4) << 2);
#pragma unroll
    for (int j = 0; j < 4; ++j) {
        const int col = col0 + 16 * j;
        if (col >= N) continue;
        const float bv = biasScale * bias[col];
#pragma unroll
        for (int i = 0; i < 4; ++i) {
#pragma unroll
            for (int r = 0; r < 4; ++r) {
                const int lrow = lrow0 + 16 * i + r;
                const int row = bm + lrow;
                if (row >= Mrows) continue;
                const float v = alpha * acc[i][j][r] + bv;
                if (v >= stau[lrow & 127]) {
                    const unsigned uu = __float_as_uint(v);
                    const unsigned key = (uu & 0x80000000u) ? ~uu : (uu | 0x80000000u);
                    const int s = atomicAdd(&lcnt[lrow & 127], 1);
                    if (s < SLOTS)
                        lcand[lrow & 127][s] = ((u64)(key ^ 0xffffffffu) << 32) | (unsigned)col;
                }
            }
        }
    }
    __syncthreads();
    if (tid < 128) {
        const int row = bm + tid;
        int c = lcnt[tid]; if (c > SLOTS) c = SLOTS;
        if (row < Mrows) {
            const size_t cell = (size_t)nt * Mrows + row;   // coalesced
            cnt2[cell] = c;
            u64* dst = pool + cell * SLOTS;
            for (int s = 0; s < c; ++s) dst[s] = lcand[tid][s];
        }
    }
}

// ---------------------------------------------------------------------------
// LayerNorm variants + small helpers
// ---------------------------------------------------------------------------
__global__ void ln_f2h_kernel(const float* __restrict__ X, const float* __restrict__ g,
                              const float* __restrict__ b, _Float16* __restrict__ Y, int M)
{
    const int row = blockIdx.x * 4 + (threadIdx.x >> 6);
    const int lane = threadIdx.x & 63;
    if (row >= M) return;
    const float* x = X + (size_t)row * D_MAIN;
    float v[4]; float s = 0.f;
#pragma unroll
    for (int i = 0; i < 4; ++i) { v[i] = x[lane + 64 * i]; s += v[i]; }
#pragma unroll
    for (int o = 32; o > 0; o >>= 1) s += __shfl_xor(s, o);
    const float mu = s * (1.f / D_MAIN);
    float vs = 0.f;
#pragma unroll
    for (int i = 0; i < 4; ++i) { const float d = v[i] - mu; vs += d * d; }
#pragma unroll
    for (int o = 32; o > 0; o >>= 1) vs += __shfl_xor(vs, o);
    const float inv = rsqrtf(vs * (1.f / D_MAIN) + 1e-5f);
    _Float16* y = Y + (size_t)row * D_MAIN;
#pragma unroll
    for (int i = 0; i < 4; ++i) {
        const int d = lane + 64 * i;
        y[d] = (_Float16)((v[i] - mu) * inv * g[d] + b[d]);
    }
}

__global__ void ln_h2h_kernel(const _Float16* __restrict__ X, const float* __restrict__ g,
                              const float* __restrict__ b, _Float16* __restrict__ Y, int M)
{
    const int row = blockIdx.x * 4 + (threadIdx.x >> 6);
    const int lane = threadIdx.x & 63;
    if (row >= M) return;
    const _Float16* x = X + (size_t)row * D_MAIN;
    float v[4]; float s = 0.f;
#pragma unroll
    for (int i = 0; i < 4; ++i) { v[i] = (float)x[lane + 64 * i]; s += v[i]; }
#pragma unroll
    for (int o = 32; o > 0; o >>= 1) s += __shfl_xor(s, o);
    const float mu = s * (1.f / D_MAIN);
    float vs = 0.f;
#pragma unroll
    for (int i = 0; i < 4; ++i) { const float d = v[i] - mu; vs += d * d; }
#pragma unroll
    for (int o = 32; o > 0; o >>= 1) vs += __shfl_xor(vs, o);
    const float inv = rsqrtf(vs * (1.f / D_MAIN) + 1e-5f);
    _Float16* y = Y + (size_t)row * D_MAIN;
#pragma unroll
    for (int i = 0; i < 4; ++i) {
        const int d = lane + 64 * i;
        y[d] = (_Float16)((v[i] - mu) * inv * g[d] + b[d]);
    }
}

// rowsq + sampled-row gather fused
__global__ void rowsq_sample(const float* __restrict__ X, float* __restrict__ sq,
                             const bf* __restrict__ ckh,
                             bf* __restrict__ ckh_s, float* __restrict__ sqc_s, int M)
{
    const int row = blockIdx.x * 4 + (threadIdx.x >> 6);
    const int lane = threadIdx.x & 63;
    if (row >= M) return;
    const float* x = X + (size_t)row * D_MAIN;
    float s = 0.f;
#pragma unroll
    for (int i = 0; i < 4; ++i) { const float v = x[lane + 64 * i]; s += v * v; }
#pragma unroll
    for (int o = 32; o > 0; o >>= 1) s += __shfl_xor(s, o);
    if (lane == 0) sq[row] = s;
    if ((row & 15) == 0) {
        const int r = row >> 4;
        if (r < NS) {
            const bf* srcp = ckh + (size_t)row * D_MAIN;
            bf* dstp = ckh_s + (size_t)r * D_MAIN;
            *(short4*)(dstp + lane * 4) = *(const short4*)(srcp + lane * 4);
            if (lane == 0) sqc_s[r] = s;
        }
    }
}

__global__ void head_kernel(const float* __restrict__ X, const float* __restrict__ g,
                            const float* __restrict__ b, const float* __restrict__ W,
                            const float* __restrict__ bh, float* __restrict__ out, int M)
{
    const int row = blockIdx.x * 4 + (threadIdx.x >> 6);
    const int lane = threadIdx.x & 63;
    if (row >= M) return;
    const float* x = X + (size_t)row * D_MAIN;
    float v[4]; float s = 0.f;
#pragma unroll
    for (int i = 0; i < 4; ++i) { v[i] = x[lane + 64 * i]; s += v[i]; }
#pragma unroll
    for (int o = 32; o > 0; o >>= 1) s += __shfl_xor(s, o);
    const float mu = s * (1.f / D_MAIN);
    float vs = 0.f;
#pragma unroll
    for (int i = 0; i < 4; ++i) { const float d = v[i] - mu; vs += d * d; }
#pragma unroll
    for (int o = 32; o > 0; o >>= 1) vs += __shfl_xor(vs, o);
    const float inv = rsqrtf(vs * (1.f / D_MAIN) + 1e-5f);
    float acc = 0.f;
#pragma unroll
    for (int i = 0; i < 4; ++i) {
        const int d = lane + 64 * i;
        float o_ = (v[i] - mu) * inv * g[d] + b[d];
        o_ = fmaxf(o_, 0.f);
        acc += o_ * W[d];
    }
#pragma unroll
    for (int o = 32; o > 0; o >>= 1) acc += __shfl_xor(acc, o);
    if (lane == 0) out[row] = acc + bh[0];
}

// One-shot conversion of all weights/inputs (10 arrays, one launch).
__global__ void conv_all(
    const float* __restrict__ W_in, const float* __restrict__ W0a,
    const float* __restrict__ W0b, const float* __restrict__ W_k,
    const float* __restrict__ Xtr, const float* __restrict__ W_t1,
    const float* __restrict__ W_t2, const float* __restrict__ X,
    const float* __restrict__ W1a, const float* __restrict__ W1b,
    _Float16* __restrict__ Win16, _Float16* __restrict__ W0a16,
    _Float16* __restrict__ W0b16, _Float16* __restrict__ Wk16,
    _Float16* __restrict__ Xtr16, bf* __restrict__ Wt1b, bf* __restrict__ Wt2b,
    _Float16* __restrict__ X16, _Float16* __restrict__ W1a16,
    _Float16* __restrict__ W1b16)
{
    const long n1 = D_MAIN * D_IN;
    const long n2 = D_BLOCK * D_MAIN;
    const long n3 = D_MAIN * D_BLOCK;
    const long n4 = D_MAIN * D_MAIN;
    const long n5 = (long)NTRAIN * D_IN;
    const long n6 = D_BLOCK * D_MAIN;
    const long n7 = (long)D_MAIN * D_BLOCK;
    const long n8 = (long)NQ * D_IN;
    const long n9 = D_BLOCK * D_MAIN;
    const long n10 = D_MAIN * D_BLOCK;
    const long total = n1 + n2 + n3 + n4 + n5 + n6 + n7 + n8 + n9 + n10;
    for (long i = (long)blockIdx.x * 256 + threadIdx.x; i < total;
         i += (long)gridDim.x * 256) {
        long r = i;
        if (r < n1) { Win16[r] = (_Float16)W_in[r]; continue; } r -= n1;
        if (r < n2) { W0a16[r] = (_Float16)W0a[r]; continue; } r -= n2;
        if (r < n3) { W0b16[r] = (_Float16)W0b[r]; continue; } r -= n3;
        if (r < n4) { Wk16[r] = (_Float16)W_k[r]; continue; } r -= n4;
        if (r < n5) { Xtr16[r] = (_Float16)Xtr[r]; continue; } r -= n5;
        if (r < n6) { Wt1b[r] = __float2bfloat16(W_t1[r]); continue; } r -= n6;
        if (r < n7) { Wt2b[r] = __float2bfloat16(W_t2[r]); continue; } r -= n7;
        if (r < n8) { X16[r] = (_Float16)X[r]; continue; } r -= n8;
        if (r < n9) { W1a16[r] = (_Float16)W1a[r]; continue; } r -= n9;
        W1b16[r] = (_Float16)W1b[r];
    }
}

// tau[q] = exact TH_RANK-th largest sample score via 4-level radix select.
__global__ __launch_bounds__(256) void thresh_kernel(
    const float* __restrict__ ss, float* __restrict__ tau)
{
    const int q = blockIdx.x, tid = threadIdx.x;
    __shared__ union {
        unsigned h12[2][4096];
        struct { unsigned h8[4][256]; unsigned A[2048]; unsigned B[2048]; } r;
    } u;
    __shared__ unsigned cs[256];
    __shared__ int sh_bin, sh_need, cc;

    for (int i = tid; i < 8192; i += 256) ((unsigned*)u.h12)[i] = 0;
    __syncthreads();
    const int rep2 = (tid >> 7) & 1;
    for (int i = tid; i < NS; i += 256) {
        const unsigned uu = __float_as_uint(ss[(size_t)q * NS + i]);
        const unsigned key = (uu & 0x80000000u) ? ~uu : (uu | 0x80000000u);
        atomicAdd(&u.h12[rep2][key >> 20], 1u);
    }
    __syncthreads();
    unsigned s = 0;
    for (int b = tid * 16; b < tid * 16 + 16; ++b) s += u.h12[0][b] + u.h12[1][b];
    cs[tid] = s;
    __syncthreads();
    if (tid == 0) {
        unsigned cum = 0; int g = 255;
        for (; g > 0; --g) {
            if (cum + cs[g] >= (unsigned)TH_RANK) break;
            cum += cs[g];
        }
        int b = g * 16;
        for (int bb = g * 16 + 15; bb >= g * 16; --bb) {
            const unsigned c = u.h12[0][bb] + u.h12[1][bb];
            if (cum + c >= (unsigned)TH_RANK) { b = bb; break; }
            cum += c;
        }
        sh_bin = b; sh_need = TH_RANK - (int)cum; cc = 0;
    }
    __syncthreads();
    const unsigned bin12 = (unsigned)sh_bin;
    for (int i = tid; i < NS; i += 256) {
        const unsigned uu = __float_as_uint(ss[(size_t)q * NS + i]);
        const unsigned key = (uu & 0x80000000u) ? ~uu : (uu | 0x80000000u);
        if ((key >> 20) == bin12) {
            const int p = atomicAdd(&cc, 1);
            if (p < 2048) u.r.A[p] = key;
        }
    }
    __syncthreads();
    int E = cc < 2048 ? cc : 2048;
    unsigned* src = u.r.A;
    unsigned* dst = u.r.B;
    const int rep4 = tid >> 6;
    for (int lvl = 0; lvl < 3; ++lvl) {
        const int sh = (lvl == 0) ? 12 : (lvl == 1) ? 4 : 0;
        const unsigned msk = (lvl == 2) ? 15u : 255u;
        const int nb = (lvl == 2) ? 16 : 256;
        for (int i = tid; i < 1024; i += 256) ((unsigned*)u.r.h8)[i] = 0;
        if (tid == 0) cc = 0;
        __syncthreads();
        for (int e = tid; e < E; e += 256) atomicAdd(&u.r.h8[rep4][(src[e] >> sh) & msk], 1u);
        __syncthreads();
        if (tid == 0) {
            const int need = sh_need;
            unsigned cum = 0; int b = nb - 1;
            for (; b > 0; --b) {
                const unsigned c = u.r.h8[0][b] + u.r.h8[1][b] + u.r.h8[2][b] + u.r.h8[3][b];
                if (cum + c >= (unsigned)need) break;
                cum += c;
            }
            sh_bin = b; sh_need = need - (int)cum;
        }
        __syncthreads();
        const unsigned b = (unsigned)sh_bin;
        for (int e = tid; e < E; e += 256) {
            if (((src[e] >> sh) & msk) == b) {
                const int p = atomicAdd(&cc, 1);
                if (p < 2048) dst[p] = src[e];
            }
        }
        __syncthreads();
        E = cc < 2048 ? cc : 2048;
        unsigned* t = src; src = dst; dst = t;
        __syncthreads();
    }
    if (tid == 0) {
        const unsigned key = src[0];
        const unsigned uu = (key & 0x80000000u) ? (key & 0x7fffffffu) : ~key;
        tau[q] = __uint_as_float(uu);
    }
}

// per chunk-local query: gather candidates from transposed (cnt2, pool) cells,
// then top-128 by (score desc, col asc) via bitonic over dynamic pow-2 size.
__global__ __launch_bounds__(256) void select_kernel(
    const u64* __restrict__ pool, const int* __restrict__ cnt2,
    int* __restrict__ idx128, int nN, int q0, int Mrows)
{
    const int q = blockIdx.x, tid = threadIdx.x;
    __shared__ u64 k[CAND_CAP];
    __shared__ int lc;
    if (tid == 0) lc = 0;
    __syncthreads();
    for (int t = tid; t < nN; t += 256) {
        const size_t cell = (size_t)t * Mrows + q;
        const int c = cnt2[cell];
        const u64* src = pool + cell * SLOTS;
        for (int s = 0; s < c; ++s) {
            const int p = atomicAdd(&lc, 1);
            if (p < CAND_CAP) k[p] = src[s];
        }
    }
    __syncthreads();
    int E = lc; if (E > CAND_CAP) E = CAND_CAP;
    int P = K_PRE; while (P < E) P <<= 1;
    for (int i = tid; i < P; i += 256)
        if (i >= E) k[i] = ~0ull;
    __syncthreads();
    for (int kk = 2; kk <= P; kk <<= 1) {
        for (int j = kk >> 1; j > 0; j >>= 1) {
            for (int i = tid; i < P; i += 256) {
                const int ixj = i ^ j;
                if (ixj > i) {
                    const bool up = ((i & kk) == 0);
                    const u64 a = k[i], b2 = k[ixj];
                    if ((a > b2) == up) { k[i] = b2; k[ixj] = a; }
                }
            }
            __syncthreads();
        }
    }
    if (tid < K_PRE) {
        const u64 e = (tid < E) ? k[tid] : k[0];
        idx128[(size_t)(q0 + q) * K_PRE + tid] = (int)(e & 0xffffffffu);
    }
}

// ---------------------------------------------------------------------------
// Exact re-rank + fused diff write: fp32 d2 over 128 candidates, top-96 with
// (d2, idx) tie rule, sims out; then writes bf16 diff rows for the 96 winners.
// ---------------------------------------------------------------------------
__global__ __launch_bounds__(256) void rerank_kernel(
    const float* __restrict__ k_q, const float* __restrict__ ck,
    const int* __restrict__ idx128, int* __restrict__ idx96,
    float* __restrict__ sims96, bf* __restrict__ diff)
{
    const int q = blockIdx.x;
    const int tid = threadIdx.x;
    const int w = tid >> 6, lam = tid & 63;
    __shared__ float kq[D_MAIN];
    __shared__ u64 keys[K_PRE];
    kq[tid] = k_q[(size_t)q * D_MAIN + tid];
    __syncthreads();

    for (int c = w * 32; c < w * 32 + 32; ++c) {
        const int j = idx128[(size_t)q * K_PRE + c];
        const float4 cv = *(const float4*)(ck + (size_t)j * D_MAIN + lam * 4);
        const float d0 = kq[lam * 4 + 0] - cv.x;
        const float d1 = kq[lam * 4 + 1] - cv.y;
        const float d2_ = kq[lam * 4 + 2] - cv.z;
        const float d3 = kq[lam * 4 + 3] - cv.w;
        float s = d0 * d0 + d1 * d1 + d2_ * d2_ + d3 * d3;
#pragma unroll
        for (int o = 32; o > 0; o >>= 1) s += __shfl_xor(s, o);
        if (lam == 0)
            keys[c] = ((u64)__float_as_uint(s) << 32) | (unsigned)j;
    }
    __syncthreads();

    for (int k = 2; k <= K_PRE; k <<= 1) {
        for (int j = k >> 1; j > 0; j >>= 1) {
            if (tid < K_PRE) {
                const int ixj = tid ^ j;
                if (ixj > tid) {
                    const bool up = ((tid & k) == 0);
                    const u64 a = keys[tid], b2 = keys[ixj];
                    if ((a > b2) == up) { keys[tid] = b2; keys[ixj] = a; }
                }
            }
            __syncthreads();
        }
    }
    u64 k2 = ~0ull;
    if (tid < CTX) k2 = (keys[tid] << 32) | (keys[tid] >> 32);
    __syncthreads();
    if (tid < K_PRE) keys[tid] = k2;
    __syncthreads();
    for (int k = 2; k <= K_PRE; k <<= 1) {
        for (int j = k >> 1; j > 0; j >>= 1) {
            if (tid < K_PRE) {
                const int ixj = tid ^ j;
                if (ixj > tid) {
                    const bool up = ((tid & k) == 0);
                    const u64 a = keys[tid], b2 = keys[ixj];
                    if ((a > b2) == up) { keys[tid] = b2; keys[ixj] = a; }
                }
            }
            __syncthreads();
        }
    }
    if (tid < CTX) {
        idx96[(size_t)q * CTX + tid] = (int)(keys[tid] >> 32);
        sims96[(size_t)q * CTX + tid] = -__uint_as_float((unsigned)(keys[tid] & 0xffffffffu));
    }
    __syncthreads();
    for (int c = w; c < CTX; c += 4) {
        const int j = (int)(keys[c] >> 32);
        const float4 cv = *(const float4*)(ck + (size_t)j * D_MAIN + lam * 4);
        bf tmp[4];
        tmp[0] = __float2bfloat16(kq[lam * 4 + 0] - cv.x);
        tmp[1] = __float2bfloat16(kq[lam * 4 + 1] - cv.y);
        tmp[2] = __float2bfloat16(kq[lam * 4 + 2] - cv.z);
        tmp[3] = __float2bfloat16(kq[lam * 4 + 3] - cv.w);
        bf* drow = diff + ((size_t)q * CTX + c) * D_MAIN + lam * 4;
        *(short4*)drow = *(short4*)tmp;
    }
}

__global__ void combine_kernel(const float* __restrict__ sscA, const int* __restrict__ idxA,
                               const float* __restrict__ ytr, const float* __restrict__ w_lab,
                               const float* __restrict__ b_lab, const bf* __restrict__ vv,
                               float* __restrict__ x_q, int q0)
{
    const int q = q0 + blockIdx.x;
    __shared__ float pr[CTX];
    __shared__ float sh_ybar;
    const int tid = threadIdx.x;
    if (tid == 0) {
        float mx = -1e30f;
        for (int c = 0; c < CTX; ++c) mx = fmaxf(mx, sscA[(size_t)q * CTX + c]);
        float sum = 0.f;
        for (int c = 0; c < CTX; ++c) {
            const float e = __expf(sscA[(size_t)q * CTX + c] - mx);
            pr[c] = e; sum += e;
        }
        const float inv = 1.f / sum;
        float yb = 0.f;
        for (int c = 0; c < CTX; ++c) {
            pr[c] *= inv;
            yb += pr[c] * ytr[idxA[(size_t)q * CTX + c]];
        }
        sh_ybar = yb;
    }
    __syncthreads();
    const int d = tid;
    float acc = 0.f;
    const bf* vq = vv + (size_t)blockIdx.x * CTX * D_MAIN;
    for (int c = 0; c < CTX; ++c) acc += pr[c] * __bfloat162float(vq[(size_t)c * D_MAIN + d]);
    x_q[(size_t)q * D_MAIN + d] += acc + sh_ybar * w_lab[d] + b_lab[d];
}

// ---------------------------------------------------------------------------
extern "C" void kernel_launch(void* const* d_in, const int* in_sizes, int n_in,
                              void* d_out, int out_size, void* d_ws, size_t ws_size,
                              hipStream_t stream)
{
    const float* X      = (const float*)d_in[0];
    const float* Xtr    = (const float*)d_in[1];
    const float* ytr    = (const float*)d_in[2];
    const float* W_in   = (const float*)d_in[3];
    const float* b_in   = (const float*)d_in[4];
    const float* W0a    = (const float*)d_in[5];
    const float* b0a    = (const float*)d_in[6];
    const float* W0b    = (const float*)d_in[7];
    const float* b0b    = (const float*)d_in[8];
    const float* g_mix  = (const float*)d_in[9];
    const float* be_mix = (const float*)d_in[10];
    const float* W_k    = (const float*)d_in[11];
    const float* b_k    = (const float*)d_in[12];
    const float* w_lab  = (const float*)d_in[13];
    const float* b_lab  = (const float*)d_in[14];
    const float* W_t1   = (const float*)d_in[15];
    const float* b_t1   = (const float*)d_in[16];
    const float* W_t2   = (const float*)d_in[17];
    const float* g_p    = (const float*)d_in[18];
    const float* be_p   = (const float*)d_in[19];
    const float* W1a    = (const float*)d_in[20];
    const float* b1a    = (const float*)d_in[21];
    const float* W1b    = (const float*)d_in[22];
    const float* b1b    = (const float*)d_in[23];
    const float* g_h    = (const float*)d_in[24];
    const float* be_h   = (const float*)d_in[25];
    const float* W_h    = (const float*)d_in[26];
    const float* b_h    = (const float*)d_in[27];
    float* out = (float*)d_out;

    char* ws = (char*)d_ws;
    size_t off = 0;
    auto alloc = [&](size_t bytes) -> void* {
        void* p = ws + off;
        off += (bytes + 255) & ~(size_t)255;
        return p;
    };
    float*     ck    = (float*)alloc((size_t)NTRAIN * D_MAIN * 4);
    bf*        ckh   = (bf*)   alloc((size_t)NTRAIN * D_MAIN * 2);
    float*     sqc   = (float*)alloc((size_t)NTRAIN * 4);
    _Float16*  Xtr16 = (_Float16*)alloc((size_t)NTRAIN * D_IN * 2);
    _Float16*  X16   = (_Float16*)alloc((size_t)NQ * D_IN * 2);
    _Float16*  Win16 = (_Float16*)alloc((size_t)D_MAIN * D_IN * 2);
    _Float16*  W0a16 = (_Float16*)alloc((size_t)D_BLOCK * D_MAIN * 2);
    _Float16*  W0b16 = (_Float16*)alloc((size_t)D_MAIN * D_BLOCK * 2);
    _Float16*  Wk16  = (_Float16*)alloc((size_t)D_MAIN * D_MAIN * 2);
    _Float16*  W1a16 = (_Float16*)alloc((size_t)D_BLOCK * D_MAIN * 2);
    _Float16*  W1b16 = (_Float16*)alloc((size_t)D_MAIN * D_BLOCK * 2);
    bf*        Wt1b  = (bf*)   alloc((size_t)D_BLOCK * D_MAIN * 2);
    bf*        Wt2b  = (bf*)   alloc((size_t)D_MAIN * D_BLOCK * 2);
    float*     x_q   = (float*)alloc((size_t)NQ * D_MAIN * 4);
    float*     k_q   = (float*)alloc((size_t)NQ * D_MAIN * 4);
    bf*        k_qb  = (bf*)   alloc((size_t)NQ * D_MAIN * 2);
    _Float16*  q_h16 = (_Float16*)alloc((size_t)NQ * D_MAIN * 2);
    _Float16*  q_t16 = (_Float16*)alloc((size_t)NQ * D_BLOCK * 2);
    _Float16*  q_l16 = (_Float16*)alloc((size_t)NQ * D_MAIN * 2);
    int*       idx128 = (int*) alloc((size_t)NQ * K_PRE * 4);
    int*       idxA  = (int*)  alloc((size_t)NQ * CTX * 4);
    float*     sscA  = (float*)alloc((size_t)NQ * CTX * 4);
    bf*        ckh_s = (bf*)   alloc((size_t)NS * D_MAIN * 2);
    float*     sqc_s = (float*)alloc((size_t)NS * 4);
    float*     tauA  = (float*)alloc((size_t)NQ * 4);

    const size_t bigOff = off;
    const size_t bigBytes = (ws_size > bigOff) ? (ws_size - bigOff) : 0;
    char* big = ws + bigOff;

    // one-shot conversions
    conv_all<<<2048, 256, 0, stream>>>(W_in, W0a, W0b, W_k, Xtr, W_t1, W_t2,
        X, W1a, W1b,
        Win16, W0a16, W0b16, Wk16, Xtr16, Wt1b, Wt2b, X16, W1a16, W1b16);

    // ---------------- encode queries (fp16 MFMA, fp32 accumulate) -----------
    {
        dim3 gA(2, (NQ + 127) / 128);
        dim3 gB(4, (NQ + 127) / 128);
        gemm_fp16<<<gA, 256, 0, stream>>>(X16, Win16, NQ, D_MAIN, D_IN,
            b_in, nullptr, nullptr, nullptr, q_h16, nullptr, 0);
        gemm_fp16<<<gB, 256, 0, stream>>>(q_h16, W0a16, NQ, D_BLOCK, D_MAIN,
            b0a, nullptr, nullptr, nullptr, q_t16, nullptr, 1);
        gemm_fp16<<<gA, 256, 0, stream>>>(q_t16, W0b16, NQ, D_MAIN, D_BLOCK,
            b0b, q_h16, nullptr, x_q, nullptr, nullptr, 0);
        ln_f2h_kernel<<<(NQ + 3) / 4, 256, 0, stream>>>(x_q, g_mix, be_mix, q_l16, NQ);
        gemm_fp16<<<gA, 256, 0, stream>>>(q_l16, Wk16, NQ, D_MAIN, D_MAIN,
            b_k, nullptr, nullptr, k_q, nullptr, k_qb, 0);
    }

    // ---------------- encode train (fp16 MFMA, in-place x; 1.5KB/row) -------
    {
        long Rmax = (long)(bigBytes / 1536);
        int R = (int)(Rmax < 100096 ? Rmax : 100096);
        R &= ~127;
        if (R < 128) R = 128;
        _Float16* h16  = (_Float16*)big;                       // R*512 B (x in-place)
        _Float16* t16  = (_Float16*)(big + (size_t)R * 512);   // R*1024 B
        _Float16* ln16 = t16;                                  // alias (t dead after W0b)
        for (int r0 = 0; r0 < NTRAIN; r0 += R) {
            const int Rc = (NTRAIN - r0 < R) ? (NTRAIN - r0) : R;
            dim3 gA(2, (Rc + 127) / 128);
            dim3 gB(4, (Rc + 127) / 128);
            gemm_fp16<<<gA, 256, 0, stream>>>(Xtr16 + (size_t)r0 * D_IN, Win16,
                Rc, D_MAIN, D_IN, b_in, nullptr, nullptr, nullptr, h16, nullptr, 0);
            gemm_fp16<<<gB, 256, 0, stream>>>(h16, W0a16, Rc, D_BLOCK, D_MAIN,
                b0a, nullptr, nullptr, nullptr, t16, nullptr, 1);
            gemm_fp16<<<gA, 256, 0, stream>>>(t16, W0b16, Rc, D_MAIN, D_BLOCK,
                b0b, h16, nullptr, nullptr, h16, nullptr, 0);
            ln_h2h_kernel<<<(Rc + 3) / 4, 256, 0, stream>>>(h16, g_mix, be_mix, ln16, Rc);
            gemm_fp16<<<gA, 256, 0, stream>>>(ln16, Wk16, Rc, D_MAIN, D_MAIN,
                b_k, nullptr, nullptr, ck + (size_t)r0 * D_MAIN, nullptr,
                ckh + (size_t)r0 * D_MAIN, 0);
        }
    }
    rowsq_sample<<<(NTRAIN + 3) / 4, 256, 0, stream>>>(ck, sqc, ckh, ckh_s, sqc_s, NTRAIN);

    // ---------------- phase A: sampled-threshold selection (atomic-free) -----
    {
        float* scores_s = (float*)big;      // 25.6 MB; dead after thresh
        dim3 gss((NS + 127) / 128, (NQ + 127) / 128);
        gemm_bf16<<<gss, 256, 0, stream>>>(k_qb, ckh_s, NQ, NS, D_MAIN,
            2.f, sqc_s, -1.f, scores_s, nullptr, 0);
        thresh_kernel<<<NQ, 256, 0, stream>>>(scores_s, tauA);

        const int nN = (NTRAIN + 127) / 128;          // 782 N-tiles
        const size_t perRow = (size_t)nN * SLOTS * 8 + (size_t)nN * 4 + 256;
        int Qc = 128, mshift = 0;
        while (Qc < NQ && (size_t)(Qc * 2) * perRow <= bigBytes) { Qc <<= 1; ++mshift; }
        const int nGroups = (nN + 7) / 8;
        for (int q0 = 0; q0 < NQ; q0 += Qc) {
            u64* pool = (u64*)big;                    // reuses scores_s space
            int* cnt2 = (int*)(big + (size_t)Qc * nN * SLOTS * 8);
            gemm_bf16_filter<<<nGroups * 8 * (Qc / 128), 256, 0, stream>>>(
                k_qb + (size_t)q0 * D_MAIN, ckh, Qc, NTRAIN, D_MAIN,
                2.f, sqc, -1.f, tauA + q0, pool, cnt2, nN, mshift);
            select_kernel<<<Qc, 256, 0, stream>>>(pool, cnt2, idx128, nN, q0, Qc);
        }
    }

    // ---------------- phase B: exact re-rank + fused diff write --------------
    const size_t diffBytes = ((size_t)NQ * CTX * D_MAIN * 2 + 255) & ~(size_t)255;
    bf* diffAll = (bf*)big;
    rerank_kernel<<<NQ, 256, 0, stream>>>(k_q, ck, idx128, idxA, sscA, diffAll);

    // ---------------- phase C: values MLP + combine (chunked) ----------------
    {
        char* cbase = big + diffBytes;
        const size_t cBytes = (bigBytes > diffBytes) ? (bigBytes - diffBytes) : 0;
        const size_t perQ = (size_t)CTX * (D_BLOCK * 2 + D_MAIN * 2); // tt + vvh
        long Qmax = (long)(cBytes / perQ);
        int Q = (int)(Qmax < NQ ? Qmax : NQ);
        if (Q < 1) Q = 1;
        for (int q0 = 0; q0 < NQ; q0 += Q) {
            const int Qc = (NQ - q0 < Q) ? (NQ - q0) : Q;
            bf* tt  = (bf*)cbase;
            bf* vvh = (bf*)(cbase + (size_t)Qc * CTX * D_BLOCK * 2);
            dim3 g1((D_BLOCK + 127) / 128, (Qc * CTX + 127) / 128);
            gemm_bf16<<<g1, 256, 0, stream>>>(diffAll + (size_t)q0 * CTX * D_MAIN, Wt1b,
                Qc * CTX, D_BLOCK, D_MAIN, 1.f, b_t1, 1.f, nullptr, tt, 1);
            dim3 g2((D_MAIN + 127) / 128, (Qc * CTX + 127) / 128);
            gemm_bf16<<<g2, 256, 0, stream>>>(tt, Wt2b, Qc * CTX, D_MAIN, D_BLOCK,
                1.f, nullptr, 0.f, nullptr, vvh, 0);
            combine_kernel<<<Qc, 256, 0, stream>>>(sscA, idxA, ytr, w_lab, b_lab, vvh, x_q, q0);
        }
    }

    // ---------------- predictor (fp16 MFMA) + head (fp32) ----------------
    {
        dim3 gA(2, (NQ + 127) / 128);
        dim3 gB(4, (NQ + 127) / 128);
        ln_f2h_kernel<<<(NQ + 3) / 4, 256, 0, stream>>>(x_q, g_p, be_p, q_l16, NQ);
        gemm_fp16<<<gB, 256, 0, stream>>>(q_l16, W1a16, NQ, D_BLOCK, D_MAIN,
            b1a, nullptr, nullptr, nullptr, q_t16, nullptr, 1);
        gemm_fp16<<<gA, 256, 0, stream>>>(q_t16, W1b16, NQ, D_MAIN, D_BLOCK,
            b1b, nullptr, x_q, x_q, nullptr, nullptr, 0);
        head_kernel<<<(NQ + 3) / 4, 256, 0, stream>>>(x_q, g_h, be_h, W_h, b_h, out, NQ);
    }
}

// Round 18
// 1089.839 us; speedup vs baseline: 1.2363x; 1.0753x over previous
//
#include <hip/hip_runtime.h>
#include <hip/hip_bf16.h>
#include <cstdint>
#include <cstddef>

#define D_IN    32
#define D_MAIN  256
#define D_BLOCK 512
#define CTX     96
#define K_PRE   128
#define NQ      1024
#define NTRAIN  100000
#define NTOT    (NQ + NTRAIN)
#define NS      6250      // sampled candidates (stride 16)
#define TH_RANK 48        // sample rank for threshold -> ~768 expected candidates
#define CAND_CAP 2048
#define SLOTS   12        // per (row, 128-col tile) candidate slots

typedef __attribute__((ext_vector_type(8))) short bf16x8;
typedef __attribute__((ext_vector_type(8))) _Float16 f16x8;
typedef __attribute__((ext_vector_type(4))) float f32x4;
typedef __hip_bfloat16 bf;
typedef unsigned long long u64;

#define GLL(gp, lp) __builtin_amdgcn_global_load_lds( \
    (const __attribute__((address_space(1))) void*)(gp), \
    (__attribute__((address_space(3))) void*)(lp), 16, 0, 0)

// ---------------------------------------------------------------------------
// Plain bf16 MFMA GEMM: C = act(alpha*(A@B^T) + biasScale*bias[n])
// 128x128 tile, BK=32, 4 waves, 16x16x32 MFMA, XOR-swizzled LDS staging.
// ---------------------------------------------------------------------------
__global__ __launch_bounds__(256) void gemm_bf16(
    const bf* __restrict__ A, const bf* __restrict__ B,
    int M, int N, int K, float alpha,
    const float* __restrict__ bias, float biasScale,
    float* __restrict__ Cf, bf* __restrict__ Ch, int relu)
{
    __shared__ __align__(16) char smem[16384];
    const int tid = threadIdx.x;
    const int w   = tid >> 6;
    const int lam = tid & 63;
    const int bm  = blockIdx.y * 128;
    const int bn  = blockIdx.x * 128;
    const int wm  = w >> 1, wn = w & 1;

    f32x4 acc[4][4];
#pragma unroll
    for (int i = 0; i < 4; ++i)
#pragma unroll
        for (int j = 0; j < 4; ++j) acc[i][j] = (f32x4){0.f, 0.f, 0.f, 0.f};

    const int r0s  = w * 16 + (lam >> 2);
    const int slot = lam & 3;
    const int g0   = slot ^ ((r0s >> 1) & 3);
    const int g1   = slot ^ (((r0s + 64) >> 1) & 3);
    const size_t strideAB = (size_t)K * 2;
    long ga0 = bm + r0s;      if (ga0 >= M) ga0 = M - 1;
    long ga1 = bm + r0s + 64; if (ga1 >= M) ga1 = M - 1;
    long gb0 = bn + r0s;      if (gb0 >= N) gb0 = N - 1;
    long gb1 = bn + r0s + 64; if (gb1 >= N) gb1 = N - 1;
    const char* pa0 = (const char*)A + (size_t)ga0 * strideAB + 16 * g0;
    const char* pa1 = (const char*)A + (size_t)ga1 * strideAB + 16 * g1;
    const char* pb0 = (const char*)B + (size_t)gb0 * strideAB + 16 * g0;
    const char* pb1 = (const char*)B + (size_t)gb1 * strideAB + 16 * g1;

    const int sread = (lam >> 4) ^ ((lam >> 1) & 3);
    const int abase = wm * 4096 + (lam & 15) * 64 + sread * 16;
    const int bbase = 8192 + wn * 4096 + (lam & 15) * 64 + sread * 16;

    for (int k0 = 0; k0 < K; k0 += 32) {
        __syncthreads();
        const size_t kb = 2 * (size_t)k0;
        GLL(pa0 + kb, smem + w * 1024);
        GLL(pa1 + kb, smem + 4096 + w * 1024);
        GLL(pb0 + kb, smem + 8192 + w * 1024);
        GLL(pb1 + kb, smem + 12288 + w * 1024);
        asm volatile("s_waitcnt vmcnt(0)" ::: "memory");
        __syncthreads();

        bf16x8 aF[4], bF[4];
#pragma unroll
        for (int i = 0; i < 4; ++i) aF[i] = *(const bf16x8*)(smem + abase + 1024 * i);
#pragma unroll
        for (int j = 0; j < 4; ++j) bF[j] = *(const bf16x8*)(smem + bbase + 1024 * j);
#pragma unroll
        for (int i = 0; i < 4; ++i)
#pragma unroll
            for (int j = 0; j < 4; ++j)
                acc[i][j] = __builtin_amdgcn_mfma_f32_16x16x32_bf16(aF[i], bF[j], acc[i][j], 0, 0, 0);
    }

    const int col0 = bn + wn * 64 + (lam & 15);
    const int row0 = bm + wm * 64 + ((lam >> 4) << 2);
#pragma unroll
    for (int j = 0; j < 4; ++j) {
        const int col = col0 + 16 * j;
        if (col >= N) continue;
        const float bv = bias ? biasScale * bias[col] : 0.f;
#pragma unroll
        for (int i = 0; i < 4; ++i) {
#pragma unroll
            for (int r = 0; r < 4; ++r) {
                const int row = row0 + 16 * i + r;
                if (row >= M) continue;
                float v = alpha * acc[i][j][r] + bv;
                if (relu) v = fmaxf(v, 0.f);
                const size_t idx = (size_t)row * N + col;
                if (Cf) Cf[idx] = v;
                if (Ch) Ch[idx] = __float2bfloat16(v);
            }
        }
    }
}

// ---------------------------------------------------------------------------
// Plain fp16 MFMA GEMM: C = act(A@B^T + bias[n] (+ res16) (+ resF))
// Outputs: fp32 / fp16 / bf16 (any subset). res16/resF may alias outputs
// (same-index read-then-write within one thread).
// ---------------------------------------------------------------------------
__global__ __launch_bounds__(256) void gemm_fp16(
    const _Float16* __restrict__ A, const _Float16* __restrict__ B,
    int M, int N, int K,
    const float* __restrict__ bias, const _Float16* res16, const float* resF,
    float* Cf, _Float16* Ch, bf* __restrict__ Cb,
    int relu)
{
    __shared__ __align__(16) char smem[16384];
    const int tid = threadIdx.x;
    const int w   = tid >> 6;
    const int lam = tid & 63;
    const int bm  = blockIdx.y * 128;
    const int bn  = blockIdx.x * 128;
    const int wm  = w >> 1, wn = w & 1;

    f32x4 acc[4][4];
#pragma unroll
    for (int i = 0; i < 4; ++i)
#pragma unroll
        for (int j = 0; j < 4; ++j) acc[i][j] = (f32x4){0.f, 0.f, 0.f, 0.f};

    const int r0s  = w * 16 + (lam >> 2);
    const int slot = lam & 3;
    const int g0   = slot ^ ((r0s >> 1) & 3);
    const int g1   = slot ^ (((r0s + 64) >> 1) & 3);
    const size_t strideAB = (size_t)K * 2;
    long ga0 = bm + r0s;      if (ga0 >= M) ga0 = M - 1;
    long ga1 = bm + r0s + 64; if (ga1 >= M) ga1 = M - 1;
    long gb0 = bn + r0s;      if (gb0 >= N) gb0 = N - 1;
    long gb1 = bn + r0s + 64; if (gb1 >= N) gb1 = N - 1;
    const char* pa0 = (const char*)A + (size_t)ga0 * strideAB + 16 * g0;
    const char* pa1 = (const char*)A + (size_t)ga1 * strideAB + 16 * g1;
    const char* pb0 = (const char*)B + (size_t)gb0 * strideAB + 16 * g0;
    const char* pb1 = (const char*)B + (size_t)gb1 * strideAB + 16 * g1;

    const int sread = (lam >> 4) ^ ((lam >> 1) & 3);
    const int abase = wm * 4096 + (lam & 15) * 64 + sread * 16;
    const int bbase = 8192 + wn * 4096 + (lam & 15) * 64 + sread * 16;

    for (int k0 = 0; k0 < K; k0 += 32) {
        __syncthreads();
        const size_t kb = 2 * (size_t)k0;
        GLL(pa0 + kb, smem + w * 1024);
        GLL(pa1 + kb, smem + 4096 + w * 1024);
        GLL(pb0 + kb, smem + 8192 + w * 1024);
        GLL(pb1 + kb, smem + 12288 + w * 1024);
        asm volatile("s_waitcnt vmcnt(0)" ::: "memory");
        __syncthreads();

        f16x8 aF[4], bF[4];
#pragma unroll
        for (int i = 0; i < 4; ++i) aF[i] = *(const f16x8*)(smem + abase + 1024 * i);
#pragma unroll
        for (int j = 0; j < 4; ++j) bF[j] = *(const f16x8*)(smem + bbase + 1024 * j);
#pragma unroll
        for (int i = 0; i < 4; ++i)
#pragma unroll
            for (int j = 0; j < 4; ++j)
                acc[i][j] = __builtin_amdgcn_mfma_f32_16x16x32_f16(aF[i], bF[j], acc[i][j], 0, 0, 0);
    }

    const int col0 = bn + wn * 64 + (lam & 15);
    const int row0 = bm + wm * 64 + ((lam >> 4) << 2);
#pragma unroll
    for (int j = 0; j < 4; ++j) {
        const int col = col0 + 16 * j;
        if (col >= N) continue;
        const float bv = bias ? bias[col] : 0.f;
#pragma unroll
        for (int i = 0; i < 4; ++i) {
#pragma unroll
            for (int r = 0; r < 4; ++r) {
                const int row = row0 + 16 * i + r;
                if (row >= M) continue;
                float v = acc[i][j][r] + bv;
                const size_t idx = (size_t)row * N + col;
                if (res16) v += (float)res16[idx];
                if (resF)  v += resF[idx];
                if (relu) v = fmaxf(v, 0.f);
                if (Cf) Cf[idx] = v;
                if (Ch) Ch[idx] = (_Float16)v;
                if (Cb) Cb[idx] = __float2bfloat16(v);
            }
        }
    }
}

// ---------------------------------------------------------------------------
// Filter GEMM (BM=128) over a chunk of Mrows query rows.
// XCD-pinned 1D grid: b -> nl=b&7, mt=(b>>3)&(mtiles-1), nt=(b>>(3+mshift))*8+nl.
// ATOMIC-FREE epilogue, COALESCED cells (nt*Mrows + row).
// ---------------------------------------------------------------------------
__global__ __launch_bounds__(256) void gemm_bf16_filter(
    const bf* __restrict__ A, const bf* __restrict__ B,
    int Mrows, int N, int K, float alpha,
    const float* __restrict__ bias, float biasScale,
    const float* __restrict__ tau,
    u64* __restrict__ pool, int* __restrict__ cnt2, int nN, int mshift)
{
    __shared__ __align__(16) char smem[16384];
    __shared__ int lcnt[128];
    __shared__ float stau[128];
    __shared__ u64 lcand[128][SLOTS];
    const int bidx = blockIdx.x;
    const int nl = bidx & 7;
    const int mt = (bidx >> 3) & ((1 << mshift) - 1);
    const int nt = (bidx >> (3 + mshift)) * 8 + nl;
    if (nt >= nN) return;
    const int bm = mt * 128;
    const int bn = nt * 128;

    const int tid = threadIdx.x;
    const int w   = tid >> 6;
    const int lam = tid & 63;
    const int wm  = w >> 1, wn = w & 1;

    if (tid < 128) { lcnt[tid] = 0; stau[tid] = tau[bm + tid]; }

    f32x4 acc[4][4];
#pragma unroll
    for (int i = 0; i < 4; ++i)
#pragma unroll
        for (int j = 0; j < 4; ++j) acc[i][j] = (f32x4){0.f, 0.f, 0.f, 0.f};

    const int r0s  = w * 16 + (lam >> 2);
    const int slot = lam & 3;
    const int g0   = slot ^ ((r0s >> 1) & 3);
    const int g1   = slot ^ (((r0s + 64) >> 1) & 3);
    const size_t strideAB = (size_t)K * 2;
    long ga0 = bm + r0s;      if (ga0 >= Mrows) ga0 = Mrows - 1;
    long ga1 = bm + r0s + 64; if (ga1 >= Mrows) ga1 = Mrows - 1;
    long gb0 = bn + r0s;      if (gb0 >= N) gb0 = N - 1;
    long gb1 = bn + r0s + 64; if (gb1 >= N) gb1 = N - 1;
    const char* pa0 = (const char*)A + (size_t)ga0 * strideAB + 16 * g0;
    const char* pa1 = (const char*)A + (size_t)ga1 * strideAB + 16 * g1;
    const char* pb0 = (const char*)B + (size_t)gb0 * strideAB + 16 * g0;
    const char* pb1 = (const char*)B + (size_t)gb1 * strideAB + 16 * g1;

    const int sread = (lam >> 4) ^ ((lam >> 1) & 3);
    const int abase = wm * 4096 + (lam & 15) * 64 + sread * 16;
    const int bbase = 8192 + wn * 4096 + (lam & 15) * 64 + sread * 16;

    for (int k0 = 0; k0 < K; k0 += 32) {
        __syncthreads();
        const size_t kb = 2 * (size_t)k0;
        GLL(pa0 + kb, smem + w * 1024);
        GLL(pa1 + kb, smem + 4096 + w * 1024);
        GLL(pb0 + kb, smem + 8192 + w * 1024);
        GLL(pb1 + kb, smem + 12288 + w * 1024);
        asm volatile("s_waitcnt vmcnt(0)" ::: "memory");
        __syncthreads();

        bf16x8 aF[4], bF[4];
#pragma unroll
        for (int i = 0; i < 4; ++i) aF[i] = *(const bf16x8*)(smem + abase + 1024 * i);
#pragma unroll
        for (int j = 0; j < 4; ++j) bF[j] = *(const bf16x8*)(smem + bbase + 1024 * j);
#pragma unroll
        for (int i = 0; i < 4; ++i)
#pragma unroll
            for (int j = 0; j < 4; ++j)
                acc[i][j] = __builtin_amdgcn_mfma_f32_16x16x32_bf16(aF[i], bF[j], acc[i][j], 0, 0, 0);
    }

    const int col0 = bn + wn * 64 + (lam & 15);
    const int lrow0 = wm * 64 + ((lam >> 4) << 2);
#pragma unroll
    for (int j = 0; j < 4; ++j) {
        const int col = col0 + 16 * j;
        if (col >= N) continue;
        const float bv = biasScale * bias[col];
#pragma unroll
        for (int i = 0; i < 4; ++i) {
#pragma unroll
            for (int r = 0; r < 4; ++r) {
                const int lrow = lrow0 + 16 * i + r;
                const int row = bm + lrow;
                if (row >= Mrows) continue;
                const float v = alpha * acc[i][j][r] + bv;
                if (v >= stau[lrow & 127]) {
                    const unsigned uu = __float_as_uint(v);
                    const unsigned key = (uu & 0x80000000u) ? ~uu : (uu | 0x80000000u);
                    const int s = atomicAdd(&lcnt[lrow & 127], 1);
                    if (s < SLOTS)
                        lcand[lrow & 127][s] = ((u64)(key ^ 0xffffffffu) << 32) | (unsigned)col;
                }
            }
        }
    }
    __syncthreads();
    if (tid < 128) {
        const int row = bm + tid;
        int c = lcnt[tid]; if (c > SLOTS) c = SLOTS;
        if (row < Mrows) {
            const size_t cell = (size_t)nt * Mrows + row;   // coalesced
            cnt2[cell] = c;
            u64* dst = pool + cell * SLOTS;
            for (int s = 0; s < c; ++s) dst[s] = lcand[tid][s];
        }
    }
}

// ---------------------------------------------------------------------------
// LayerNorm variants + small helpers
// ---------------------------------------------------------------------------
__global__ void ln_f2h_kernel(const float* __restrict__ X, const float* __restrict__ g,
                              const float* __restrict__ b, _Float16* __restrict__ Y, int M)
{
    const int row = blockIdx.x * 4 + (threadIdx.x >> 6);
    const int lane = threadIdx.x & 63;
    if (row >= M) return;
    const float* x = X + (size_t)row * D_MAIN;
    float v[4]; float s = 0.f;
#pragma unroll
    for (int i = 0; i < 4; ++i) { v[i] = x[lane + 64 * i]; s += v[i]; }
#pragma unroll
    for (int o = 32; o > 0; o >>= 1) s += __shfl_xor(s, o);
    const float mu = s * (1.f / D_MAIN);
    float vs = 0.f;
#pragma unroll
    for (int i = 0; i < 4; ++i) { const float d = v[i] - mu; vs += d * d; }
#pragma unroll
    for (int o = 32; o > 0; o >>= 1) vs += __shfl_xor(vs, o);
    const float inv = rsqrtf(vs * (1.f / D_MAIN) + 1e-5f);
    _Float16* y = Y + (size_t)row * D_MAIN;
#pragma unroll
    for (int i = 0; i < 4; ++i) {
        const int d = lane + 64 * i;
        y[d] = (_Float16)((v[i] - mu) * inv * g[d] + b[d]);
    }
}

__global__ void ln_h2h_kernel(const _Float16* __restrict__ X, const float* __restrict__ g,
                              const float* __restrict__ b, _Float16* __restrict__ Y, int M)
{
    const int row = blockIdx.x * 4 + (threadIdx.x >> 6);
    const int lane = threadIdx.x & 63;
    if (row >= M) return;
    const _Float16* x = X + (size_t)row * D_MAIN;
    float v[4]; float s = 0.f;
#pragma unroll
    for (int i = 0; i < 4; ++i) { v[i] = (float)x[lane + 64 * i]; s += v[i]; }
#pragma unroll
    for (int o = 32; o > 0; o >>= 1) s += __shfl_xor(s, o);
    const float mu = s * (1.f / D_MAIN);
    float vs = 0.f;
#pragma unroll
    for (int i = 0; i < 4; ++i) { const float d = v[i] - mu; vs += d * d; }
#pragma unroll
    for (int o = 32; o > 0; o >>= 1) vs += __shfl_xor(vs, o);
    const float inv = rsqrtf(vs * (1.f / D_MAIN) + 1e-5f);
    _Float16* y = Y + (size_t)row * D_MAIN;
#pragma unroll
    for (int i = 0; i < 4; ++i) {
        const int d = lane + 64 * i;
        y[d] = (_Float16)((v[i] - mu) * inv * g[d] + b[d]);
    }
}

// fp16 -> fp32 copy (query-row x recovery)
__global__ void h2f_kernel(const _Float16* __restrict__ in, float* __restrict__ out, int n)
{
    const int i = blockIdx.x * 256 + threadIdx.x;
    if (i < n) out[i] = (float)in[i];
}

// rowsq + sampled-row gather fused (over TRAIN rows of the concatenated ck)
__global__ void rowsq_sample(const float* __restrict__ X, float* __restrict__ sq,
                             const bf* __restrict__ ckh,
                             bf* __restrict__ ckh_s, float* __restrict__ sqc_s, int M)
{
    const int row = blockIdx.x * 4 + (threadIdx.x >> 6);
    const int lane = threadIdx.x & 63;
    if (row >= M) return;
    const float* x = X + (size_t)row * D_MAIN;
    float s = 0.f;
#pragma unroll
    for (int i = 0; i < 4; ++i) { const float v = x[lane + 64 * i]; s += v * v; }
#pragma unroll
    for (int o = 32; o > 0; o >>= 1) s += __shfl_xor(s, o);
    if (lane == 0) sq[row] = s;
    if ((row & 15) == 0) {
        const int r = row >> 4;
        if (r < NS) {
            const bf* srcp = ckh + (size_t)row * D_MAIN;
            bf* dstp = ckh_s + (size_t)r * D_MAIN;
            *(short4*)(dstp + lane * 4) = *(const short4*)(srcp + lane * 4);
            if (lane == 0) sqc_s[r] = s;
        }
    }
}

__global__ void head_kernel(const float* __restrict__ X, const float* __restrict__ g,
                            const float* __restrict__ b, const float* __restrict__ W,
                            const float* __restrict__ bh, float* __restrict__ out, int M)
{
    const int row = blockIdx.x * 4 + (threadIdx.x >> 6);
    const int lane = threadIdx.x & 63;
    if (row >= M) return;
    const float* x = X + (size_t)row * D_MAIN;
    float v[4]; float s = 0.f;
#pragma unroll
    for (int i = 0; i < 4; ++i) { v[i] = x[lane + 64 * i]; s += v[i]; }
#pragma unroll
    for (int o = 32; o > 0; o >>= 1) s += __shfl_xor(s, o);
    const float mu = s * (1.f / D_MAIN);
    float vs = 0.f;
#pragma unroll
    for (int i = 0; i < 4; ++i) { const float d = v[i] - mu; vs += d * d; }
#pragma unroll
    for (int o = 32; o > 0; o >>= 1) vs += __shfl_xor(vs, o);
    const float inv = rsqrtf(vs * (1.f / D_MAIN) + 1e-5f);
    float acc = 0.f;
#pragma unroll
    for (int i = 0; i < 4; ++i) {
        const int d = lane + 64 * i;
        float o_ = (v[i] - mu) * inv * g[d] + b[d];
        o_ = fmaxf(o_, 0.f);
        acc += o_ * W[d];
    }
#pragma unroll
    for (int o = 32; o > 0; o >>= 1) acc += __shfl_xor(acc, o);
    if (lane == 0) out[row] = acc + bh[0];
}

// One-shot conversion of all weights/inputs (one launch). Encoder input is
// the CONCATENATED [X; Xtr] fp16 buffer.
__global__ void conv_all(
    const float* __restrict__ W_in, const float* __restrict__ W0a,
    const float* __restrict__ W0b, const float* __restrict__ W_k,
    const float* __restrict__ X, const float* __restrict__ Xtr,
    const float* __restrict__ W_t1, const float* __restrict__ W_t2,
    const float* __restrict__ W1a, const float* __restrict__ W1b,
    _Float16* __restrict__ Win16, _Float16* __restrict__ W0a16,
    _Float16* __restrict__ W0b16, _Float16* __restrict__ Wk16,
    _Float16* __restrict__ enc16, bf* __restrict__ Wt1b, bf* __restrict__ Wt2b,
    _Float16* __restrict__ W1a16, _Float16* __restrict__ W1b16)
{
    const long n1 = D_MAIN * D_IN;
    const long n2 = D_BLOCK * D_MAIN;
    const long n3 = D_MAIN * D_BLOCK;
    const long n4 = D_MAIN * D_MAIN;
    const long n5 = (long)NQ * D_IN;
    const long n6 = (long)NTRAIN * D_IN;
    const long n7 = D_BLOCK * D_MAIN;
    const long n8 = (long)D_MAIN * D_BLOCK;
    const long n9 = D_BLOCK * D_MAIN;
    const long n10 = D_MAIN * D_BLOCK;
    const long total = n1 + n2 + n3 + n4 + n5 + n6 + n7 + n8 + n9 + n10;
    for (long i = (long)blockIdx.x * 256 + threadIdx.x; i < total;
         i += (long)gridDim.x * 256) {
        long r = i;
        if (r < n1) { Win16[r] = (_Float16)W_in[r]; continue; } r -= n1;
        if (r < n2) { W0a16[r] = (_Float16)W0a[r]; continue; } r -= n2;
        if (r < n3) { W0b16[r] = (_Float16)W0b[r]; continue; } r -= n3;
        if (r < n4) { Wk16[r] = (_Float16)W_k[r]; continue; } r -= n4;
        if (r < n5) { enc16[r] = (_Float16)X[r]; continue; } r -= n5;
        if (r < n6) { enc16[(long)NQ * D_IN + r] = (_Float16)Xtr[r]; continue; } r -= n6;
        if (r < n7) { Wt1b[r] = __float2bfloat16(W_t1[r]); continue; } r -= n7;
        if (r < n8) { Wt2b[r] = __float2bfloat16(W_t2[r]); continue; } r -= n8;
        if (r < n9) { W1a16[r] = (_Float16)W1a[r]; continue; } r -= n9;
        W1b16[r] = (_Float16)W1b[r];
    }
}

// tau[q] = exact TH_RANK-th largest sample score via 4-level radix select.
__global__ __launch_bounds__(256) void thresh_kernel(
    const float* __restrict__ ss, float* __restrict__ tau)
{
    const int q = blockIdx.x, tid = threadIdx.x;
    __shared__ union {
        unsigned h12[2][4096];
        struct { unsigned h8[4][256]; unsigned A[2048]; unsigned B[2048]; } r;
    } u;
    __shared__ unsigned cs[256];
    __shared__ int sh_bin, sh_need, cc;

    for (int i = tid; i < 8192; i += 256) ((unsigned*)u.h12)[i] = 0;
    __syncthreads();
    const int rep2 = (tid >> 7) & 1;
    for (int i = tid; i < NS; i += 256) {
        const unsigned uu = __float_as_uint(ss[(size_t)q * NS + i]);
        const unsigned key = (uu & 0x80000000u) ? ~uu : (uu | 0x80000000u);
        atomicAdd(&u.h12[rep2][key >> 20], 1u);
    }
    __syncthreads();
    unsigned s = 0;
    for (int b = tid * 16; b < tid * 16 + 16; ++b) s += u.h12[0][b] + u.h12[1][b];
    cs[tid] = s;
    __syncthreads();
    if (tid == 0) {
        unsigned cum = 0; int g = 255;
        for (; g > 0; --g) {
            if (cum + cs[g] >= (unsigned)TH_RANK) break;
            cum += cs[g];
        }
        int b = g * 16;
        for (int bb = g * 16 + 15; bb >= g * 16; --bb) {
            const unsigned c = u.h12[0][bb] + u.h12[1][bb];
            if (cum + c >= (unsigned)TH_RANK) { b = bb; break; }
            cum += c;
        }
        sh_bin = b; sh_need = TH_RANK - (int)cum; cc = 0;
    }
    __syncthreads();
    const unsigned bin12 = (unsigned)sh_bin;
    for (int i = tid; i < NS; i += 256) {
        const unsigned uu = __float_as_uint(ss[(size_t)q * NS + i]);
        const unsigned key = (uu & 0x80000000u) ? ~uu : (uu | 0x80000000u);
        if ((key >> 20) == bin12) {
            const int p = atomicAdd(&cc, 1);
            if (p < 2048) u.r.A[p] = key;
        }
    }
    __syncthreads();
    int E = cc < 2048 ? cc : 2048;
    unsigned* src = u.r.A;
    unsigned* dst = u.r.B;
    const int rep4 = tid >> 6;
    for (int lvl = 0; lvl < 3; ++lvl) {
        const int sh = (lvl == 0) ? 12 : (lvl == 1) ? 4 : 0;
        const unsigned msk = (lvl == 2) ? 15u : 255u;
        const int nb = (lvl == 2) ? 16 : 256;
        for (int i = tid; i < 1024; i += 256) ((unsigned*)u.r.h8)[i] = 0;
        if (tid == 0) cc = 0;
        __syncthreads();
        for (int e = tid; e < E; e += 256) atomicAdd(&u.r.h8[rep4][(src[e] >> sh) & msk], 1u);
        __syncthreads();
        if (tid == 0) {
            const int need = sh_need;
            unsigned cum = 0; int b = nb - 1;
            for (; b > 0; --b) {
                const unsigned c = u.r.h8[0][b] + u.r.h8[1][b] + u.r.h8[2][b] + u.r.h8[3][b];
                if (cum + c >= (unsigned)need) break;
                cum += c;
            }
            sh_bin = b; sh_need = need - (int)cum;
        }
        __syncthreads();
        const unsigned b = (unsigned)sh_bin;
        for (int e = tid; e < E; e += 256) {
            if (((src[e] >> sh) & msk) == b) {
                const int p = atomicAdd(&cc, 1);
                if (p < 2048) dst[p] = src[e];
            }
        }
        __syncthreads();
        E = cc < 2048 ? cc : 2048;
        unsigned* t = src; src = dst; dst = t;
        __syncthreads();
    }
    if (tid == 0) {
        const unsigned key = src[0];
        const unsigned uu = (key & 0x80000000u) ? (key & 0x7fffffffu) : ~key;
        tau[q] = __uint_as_float(uu);
    }
}

// per chunk-local query: gather candidates from transposed (cnt2, pool) cells,
// then top-128 by (score desc, col asc) via bitonic over dynamic pow-2 size.
__global__ __launch_bounds__(256) void select_kernel(
    const u64* __restrict__ pool, const int* __restrict__ cnt2,
    int* __restrict__ idx128, int nN, int q0, int Mrows)
{
    const int q = blockIdx.x, tid = threadIdx.x;
    __shared__ u64 k[CAND_CAP];
    __shared__ int lc;
    if (tid == 0) lc = 0;
    __syncthreads();
    for (int t = tid; t < nN; t += 256) {
        const size_t cell = (size_t)t * Mrows + q;
        const int c = cnt2[cell];
        const u64* src = pool + cell * SLOTS;
        for (int s = 0; s < c; ++s) {
            const int p = atomicAdd(&lc, 1);
            if (p < CAND_CAP) k[p] = src[s];
        }
    }
    __syncthreads();
    int E = lc; if (E > CAND_CAP) E = CAND_CAP;
    int P = K_PRE; while (P < E) P <<= 1;
    for (int i = tid; i < P; i += 256)
        if (i >= E) k[i] = ~0ull;
    __syncthreads();
    for (int kk = 2; kk <= P; kk <<= 1) {
        for (int j = kk >> 1; j > 0; j >>= 1) {
            for (int i = tid; i < P; i += 256) {
                const int ixj = i ^ j;
                if (ixj > i) {
                    const bool up = ((i & kk) == 0);
                    const u64 a = k[i], b2 = k[ixj];
                    if ((a > b2) == up) { k[i] = b2; k[ixj] = a; }
                }
            }
            __syncthreads();
        }
    }
    if (tid < K_PRE) {
        const u64 e = (tid < E) ? k[tid] : k[0];
        idx128[(size_t)(q0 + q) * K_PRE + tid] = (int)(e & 0xffffffffu);
    }
}

// ---------------------------------------------------------------------------
// Exact re-rank + fused diff write: fp32 d2 over 128 candidates, top-96 with
// (d2, idx) tie rule, sims out; then writes bf16 diff rows for the 96 winners.
// ---------------------------------------------------------------------------
__global__ __launch_bounds__(256) void rerank_kernel(
    const float* __restrict__ k_q, const float* __restrict__ ck,
    const int* __restrict__ idx128, int* __restrict__ idx96,
    float* __restrict__ sims96, bf* __restrict__ diff)
{
    const int q = blockIdx.x;
    const int tid = threadIdx.x;
    const int w = tid >> 6, lam = tid & 63;
    __shared__ float kq[D_MAIN];
    __shared__ u64 keys[K_PRE];
    kq[tid] = k_q[(size_t)q * D_MAIN + tid];
    __syncthreads();

    for (int c = w * 32; c < w * 32 + 32; ++c) {
        const int j = idx128[(size_t)q * K_PRE + c];
        const float4 cv = *(const float4*)(ck + (size_t)j * D_MAIN + lam * 4);
        const float d0 = kq[lam * 4 + 0] - cv.x;
        const float d1 = kq[lam * 4 + 1] - cv.y;
        const float d2_ = kq[lam * 4 + 2] - cv.z;
        const float d3 = kq[lam * 4 + 3] - cv.w;
        float s = d0 * d0 + d1 * d1 + d2_ * d2_ + d3 * d3;
#pragma unroll
        for (int o = 32; o > 0; o >>= 1) s += __shfl_xor(s, o);
        if (lam == 0)
            keys[c] = ((u64)__float_as_uint(s) << 32) | (unsigned)j;
    }
    __syncthreads();

    for (int k = 2; k <= K_PRE; k <<= 1) {
        for (int j = k >> 1; j > 0; j >>= 1) {
            if (tid < K_PRE) {
                const int ixj = tid ^ j;
                if (ixj > tid) {
                    const bool up = ((tid & k) == 0);
                    const u64 a = keys[tid], b2 = keys[ixj];
                    if ((a > b2) == up) { keys[tid] = b2; keys[ixj] = a; }
                }
            }
            __syncthreads();
        }
    }
    u64 k2 = ~0ull;
    if (tid < CTX) k2 = (keys[tid] << 32) | (keys[tid] >> 32);
    __syncthreads();
    if (tid < K_PRE) keys[tid] = k2;
    __syncthreads();
    for (int k = 2; k <= K_PRE; k <<= 1) {
        for (int j = k >> 1; j > 0; j >>= 1) {
            if (tid < K_PRE) {
                const int ixj = tid ^ j;
                if (ixj > tid) {
                    const bool up = ((tid & k) == 0);
                    const u64 a = keys[tid], b2 = keys[ixj];
                    if ((a > b2) == up) { keys[tid] = b2; keys[ixj] = a; }
                }
            }
            __syncthreads();
        }
    }
    if (tid < CTX) {
        idx96[(size_t)q * CTX + tid] = (int)(keys[tid] >> 32);
        sims96[(size_t)q * CTX + tid] = -__uint_as_float((unsigned)(keys[tid] & 0xffffffffu));
    }
    __syncthreads();
    for (int c = w; c < CTX; c += 4) {
        const int j = (int)(keys[c] >> 32);
        const float4 cv = *(const float4*)(ck + (size_t)j * D_MAIN + lam * 4);
        bf tmp[4];
        tmp[0] = __float2bfloat16(kq[lam * 4 + 0] - cv.x);
        tmp[1] = __float2bfloat16(kq[lam * 4 + 1] - cv.y);
        tmp[2] = __float2bfloat16(kq[lam * 4 + 2] - cv.z);
        tmp[3] = __float2bfloat16(kq[lam * 4 + 3] - cv.w);
        bf* drow = diff + ((size_t)q * CTX + c) * D_MAIN + lam * 4;
        *(short4*)drow = *(short4*)tmp;
    }
}

__global__ void combine_kernel(const float* __restrict__ sscA, const int* __restrict__ idxA,
                               const float* __restrict__ ytr, const float* __restrict__ w_lab,
                               const float* __restrict__ b_lab, const bf* __restrict__ vv,
                               float* __restrict__ x_q, int q0)
{
    const int q = q0 + blockIdx.x;
    __shared__ float pr[CTX];
    __shared__ float sh_ybar;
    const int tid = threadIdx.x;
    if (tid == 0) {
        float mx = -1e30f;
        for (int c = 0; c < CTX; ++c) mx = fmaxf(mx, sscA[(size_t)q * CTX + c]);
        float sum = 0.f;
        for (int c = 0; c < CTX; ++c) {
            const float e = __expf(sscA[(size_t)q * CTX + c] - mx);
            pr[c] = e; sum += e;
        }
        const float inv = 1.f / sum;
        float yb = 0.f;
        for (int c = 0; c < CTX; ++c) {
            pr[c] *= inv;
            yb += pr[c] * ytr[idxA[(size_t)q * CTX + c]];
        }
        sh_ybar = yb;
    }
    __syncthreads();
    const int d = tid;
    float acc = 0.f;
    const bf* vq = vv + (size_t)blockIdx.x * CTX * D_MAIN;
    for (int c = 0; c < CTX; ++c) acc += pr[c] * __bfloat162float(vq[(size_t)c * D_MAIN + d]);
    x_q[(size_t)q * D_MAIN + d] += acc + sh_ybar * w_lab[d] + b_lab[d];
}

// ---------------------------------------------------------------------------
extern "C" void kernel_launch(void* const* d_in, const int* in_sizes, int n_in,
                              void* d_out, int out_size, void* d_ws, size_t ws_size,
                              hipStream_t stream)
{
    const float* X      = (const float*)d_in[0];
    const float* Xtr    = (const float*)d_in[1];
    const float* ytr    = (const float*)d_in[2];
    const float* W_in   = (const float*)d_in[3];
    const float* b_in   = (const float*)d_in[4];
    const float* W0a    = (const float*)d_in[5];
    const float* b0a    = (const float*)d_in[6];
    const float* W0b    = (const float*)d_in[7];
    const float* b0b    = (const float*)d_in[8];
    const float* g_mix  = (const float*)d_in[9];
    const float* be_mix = (const float*)d_in[10];
    const float* W_k    = (const float*)d_in[11];
    const float* b_k    = (const float*)d_in[12];
    const float* w_lab  = (const float*)d_in[13];
    const float* b_lab  = (const float*)d_in[14];
    const float* W_t1   = (const float*)d_in[15];
    const float* b_t1   = (const float*)d_in[16];
    const float* W_t2   = (const float*)d_in[17];
    const float* g_p    = (const float*)d_in[18];
    const float* be_p   = (const float*)d_in[19];
    const float* W1a    = (const float*)d_in[20];
    const float* b1a    = (const float*)d_in[21];
    const float* W1b    = (const float*)d_in[22];
    const float* b1b    = (const float*)d_in[23];
    const float* g_h    = (const float*)d_in[24];
    const float* be_h   = (const float*)d_in[25];
    const float* W_h    = (const float*)d_in[26];
    const float* b_h    = (const float*)d_in[27];
    float* out = (float*)d_out;

    char* ws = (char*)d_ws;
    size_t off = 0;
    auto alloc = [&](size_t bytes) -> void* {
        void* p = ws + off;
        off += (bytes + 255) & ~(size_t)255;
        return p;
    };
    float*     ckAll = (float*)alloc((size_t)NTOT * D_MAIN * 4);
    bf*        ckhAll= (bf*)   alloc((size_t)NTOT * D_MAIN * 2);
    float*     sqc   = (float*)alloc((size_t)NTRAIN * 4);
    _Float16*  enc16 = (_Float16*)alloc((size_t)NTOT * D_IN * 2);
    _Float16*  Win16 = (_Float16*)alloc((size_t)D_MAIN * D_IN * 2);
    _Float16*  W0a16 = (_Float16*)alloc((size_t)D_BLOCK * D_MAIN * 2);
    _Float16*  W0b16 = (_Float16*)alloc((size_t)D_MAIN * D_BLOCK * 2);
    _Float16*  Wk16  = (_Float16*)alloc((size_t)D_MAIN * D_MAIN * 2);
    _Float16*  W1a16 = (_Float16*)alloc((size_t)D_BLOCK * D_MAIN * 2);
    _Float16*  W1b16 = (_Float16*)alloc((size_t)D_MAIN * D_BLOCK * 2);
    bf*        Wt1b  = (bf*)   alloc((size_t)D_BLOCK * D_MAIN * 2);
    bf*        Wt2b  = (bf*)   alloc((size_t)D_MAIN * D_BLOCK * 2);
    float*     x_q   = (float*)alloc((size_t)NQ * D_MAIN * 4);
    _Float16*  q_t16 = (_Float16*)alloc((size_t)NQ * D_BLOCK * 2);
    _Float16*  q_l16 = (_Float16*)alloc((size_t)NQ * D_MAIN * 2);
    int*       idx128 = (int*) alloc((size_t)NQ * K_PRE * 4);
    int*       idxA  = (int*)  alloc((size_t)NQ * CTX * 4);
    float*     sscA  = (float*)alloc((size_t)NQ * CTX * 4);
    bf*        ckh_s = (bf*)   alloc((size_t)NS * D_MAIN * 2);
    float*     sqc_s = (float*)alloc((size_t)NS * 4);
    float*     tauA  = (float*)alloc((size_t)NQ * 4);

    // views into the concatenated encoder output
    float* k_q  = ckAll;                        // rows [0, NQ)
    bf*    k_qb = ckhAll;                       // rows [0, NQ)
    float* ck   = ckAll + (size_t)NQ * D_MAIN;  // train rows
    bf*    ckh  = ckhAll + (size_t)NQ * D_MAIN;

    const size_t bigOff = off;
    const size_t bigBytes = (ws_size > bigOff) ? (ws_size - bigOff) : 0;
    char* big = ws + bigOff;

    // one-shot conversions (queries + train concatenated into enc16)
    conv_all<<<2048, 256, 0, stream>>>(W_in, W0a, W0b, W_k, X, Xtr, W_t1, W_t2,
        W1a, W1b,
        Win16, W0a16, W0b16, Wk16, enc16, Wt1b, Wt2b, W1a16, W1b16);

    // ---------------- fused encode [X; Xtr] (fp16 MFMA, in-place x) ---------
    {
        long Rmax = (long)(bigBytes / 1536);
        int R = (int)(Rmax < 101120 ? Rmax : 101120);
        R &= ~127;
        if (R < 128) R = 128;
        _Float16* h16  = (_Float16*)big;                       // R*512 B (x in-place)
        _Float16* t16  = (_Float16*)(big + (size_t)R * 512);   // R*1024 B
        _Float16* ln16 = t16;                                  // alias (t dead after W0b)
        for (int r0 = 0; r0 < NTOT; r0 += R) {
            const int Rc = (NTOT - r0 < R) ? (NTOT - r0) : R;
            dim3 gA(2, (Rc + 127) / 128);
            dim3 gB(4, (Rc + 127) / 128);
            gemm_fp16<<<gA, 256, 0, stream>>>(enc16 + (size_t)r0 * D_IN, Win16,
                Rc, D_MAIN, D_IN, b_in, nullptr, nullptr, nullptr, h16, nullptr, 0);
            gemm_fp16<<<gB, 256, 0, stream>>>(h16, W0a16, Rc, D_BLOCK, D_MAIN,
                b0a, nullptr, nullptr, nullptr, t16, nullptr, 1);
            gemm_fp16<<<gA, 256, 0, stream>>>(t16, W0b16, Rc, D_MAIN, D_BLOCK,
                b0b, h16, nullptr, nullptr, h16, nullptr, 0);
            // recover fp32 x for query rows (global rows < NQ)
            if (r0 < NQ) {
                const int nq = ((NQ - r0) < Rc ? (NQ - r0) : Rc);
                h2f_kernel<<<(nq * D_MAIN + 255) / 256, 256, 0, stream>>>(
                    h16, x_q + (size_t)r0 * D_MAIN, nq * D_MAIN);
            }
            ln_h2h_kernel<<<(Rc + 3) / 4, 256, 0, stream>>>(h16, g_mix, be_mix, ln16, Rc);
            gemm_fp16<<<gA, 256, 0, stream>>>(ln16, Wk16, Rc, D_MAIN, D_MAIN,
                b_k, nullptr, nullptr, ckAll + (size_t)r0 * D_MAIN, nullptr,
                ckhAll + (size_t)r0 * D_MAIN, 0);
        }
    }
    rowsq_sample<<<(NTRAIN + 3) / 4, 256, 0, stream>>>(ck, sqc, ckh, ckh_s, sqc_s, NTRAIN);

    // ---------------- phase A: sampled-threshold selection (atomic-free) -----
    {
        float* scores_s = (float*)big;      // 25.6 MB; dead after thresh
        dim3 gss((NS + 127) / 128, (NQ + 127) / 128);
        gemm_bf16<<<gss, 256, 0, stream>>>(k_qb, ckh_s, NQ, NS, D_MAIN,
            2.f, sqc_s, -1.f, scores_s, nullptr, 0);
        thresh_kernel<<<NQ, 256, 0, stream>>>(scores_s, tauA);

        const int nN = (NTRAIN + 127) / 128;          // 782 N-tiles
        const size_t perRow = (size_t)nN * SLOTS * 8 + (size_t)nN * 4 + 256;
        int Qc = 128, mshift = 0;
        while (Qc < NQ && (size_t)(Qc * 2) * perRow <= bigBytes) { Qc <<= 1; ++mshift; }
        const int nGroups = (nN + 7) / 8;
        for (int q0 = 0; q0 < NQ; q0 += Qc) {
            u64* pool = (u64*)big;                    // reuses scores_s space
            int* cnt2 = (int*)(big + (size_t)Qc * nN * SLOTS * 8);
            gemm_bf16_filter<<<nGroups * 8 * (Qc / 128), 256, 0, stream>>>(
                k_qb + (size_t)q0 * D_MAIN, ckh, Qc, NTRAIN, D_MAIN,
                2.f, sqc, -1.f, tauA + q0, pool, cnt2, nN, mshift);
            select_kernel<<<Qc, 256, 0, stream>>>(pool, cnt2, idx128, nN, q0, Qc);
        }
    }

    // ---------------- phase B: exact re-rank + fused diff write --------------
    const size_t diffBytes = ((size_t)NQ * CTX * D_MAIN * 2 + 255) & ~(size_t)255;
    bf* diffAll = (bf*)big;
    rerank_kernel<<<NQ, 256, 0, stream>>>(k_q, ck, idx128, idxA, sscA, diffAll);

    // ---------------- phase C: values MLP + combine (chunked) ----------------
    {
        char* cbase = big + diffBytes;
        const size_t cBytes = (bigBytes > diffBytes) ? (bigBytes - diffBytes) : 0;
        const size_t perQ = (size_t)CTX * (D_BLOCK * 2 + D_MAIN * 2); // tt + vvh
        long Qmax = (long)(cBytes / perQ);
        int Q = (int)(Qmax < NQ ? Qmax : NQ);
        if (Q < 1) Q = 1;
        for (int q0 = 0; q0 < NQ; q0 += Q) {
            const int Qc = (NQ - q0 < Q) ? (NQ - q0) : Q;
            bf* tt  = (bf*)cbase;
            bf* vvh = (bf*)(cbase + (size_t)Qc * CTX * D_BLOCK * 2);
            dim3 g1((D_BLOCK + 127) / 128, (Qc * CTX + 127) / 128);
            gemm_bf16<<<g1, 256, 0, stream>>>(diffAll + (size_t)q0 * CTX * D_MAIN, Wt1b,
                Qc * CTX, D_BLOCK, D_MAIN, 1.f, b_t1, 1.f, nullptr, tt, 1);
            dim3 g2((D_MAIN + 127) / 128, (Qc * CTX + 127) / 128);
            gemm_bf16<<<g2, 256, 0, stream>>>(tt, Wt2b, Qc * CTX, D_MAIN, D_BLOCK,
                1.f, nullptr, 0.f, nullptr, vvh, 0);
            combine_kernel<<<Qc, 256, 0, stream>>>(sscA, idxA, ytr, w_lab, b_lab, vvh, x_q, q0);
        }
    }

    // ---------------- predictor (fp16 MFMA) + head (fp32) ----------------
    {
        dim3 gA(2, (NQ + 127) / 128);
        dim3 gB(4, (NQ + 127) / 128);
        ln_f2h_kernel<<<(NQ + 3) / 4, 256, 0, stream>>>(x_q, g_p, be_p, q_l16, NQ);
        gemm_fp16<<<gB, 256, 0, stream>>>(q_l16, W1a16, NQ, D_BLOCK, D_MAIN,
            b1a, nullptr, nullptr, nullptr, q_t16, nullptr, 1);
        gemm_fp16<<<gA, 256, 0, stream>>>(q_t16, W1b16, NQ, D_MAIN, D_BLOCK,
            b1b, nullptr, x_q, x_q, nullptr, nullptr, 0);
        head_kernel<<<(NQ + 3) / 4, 256, 0, stream>>>(x_q, g_h, be_h, W_h, b_h, out, NQ);
    }
}